// Round 1
// baseline (2979.573 us; speedup 1.0000x reference)
//
#include <hip/hip_runtime.h>
#include <hip/hip_bf16.h>

// Problem constants
#define D_MODEL 1024
#define N_HEADS 16
#define HEAD_DIM 64
#define D_LATENT 256
#define BATCH 2
#define SEQ 2048
#define M_ROWS (BATCH * SEQ)   // 4096

// ---------------------------------------------------------------------------
// Generic fp32 GEMM: C[M,N] = A[M,K] @ W[K,N] + bias[N]
// 64x64 block tile, BK=16, 256 threads, 4x4 micro-tile per thread.
// All dims here are multiples of 64 (and K of 16) so no edge guards.
// ---------------------------------------------------------------------------
__global__ __launch_bounds__(256) void gemm_f32(
    const float* __restrict__ A, const float* __restrict__ W,
    const float* __restrict__ bias, float* __restrict__ C,
    int M, int N, int K)
{
    __shared__ float As[16][64];   // [k][m]
    __shared__ float Bs[16][64];   // [k][n]
    const int t  = threadIdx.x;
    const int m0 = blockIdx.y * 64;
    const int n0 = blockIdx.x * 64;
    const int tr = t >> 4;         // 0..15 (row group)
    const int tc = t & 15;         // 0..15 (col group)

    float acc[4][4] = {};

    for (int k0 = 0; k0 < K; k0 += 16) {
        // Load A tile 64x16 (transposed into As[k][m])
        #pragma unroll
        for (int i = 0; i < 4; ++i) {
            int idx = t + i * 256;          // 0..1023
            int r = idx >> 4, c = idx & 15;
            As[c][r] = A[(size_t)(m0 + r) * K + k0 + c];
        }
        // Load B tile 16x64
        #pragma unroll
        for (int i = 0; i < 4; ++i) {
            int idx = t + i * 256;
            int r = idx >> 6, c = idx & 63;
            Bs[r][c] = W[(size_t)(k0 + r) * N + n0 + c];
        }
        __syncthreads();
        #pragma unroll
        for (int kk = 0; kk < 16; ++kk) {
            float a[4], b[4];
            #pragma unroll
            for (int i = 0; i < 4; ++i) a[i] = As[kk][tr * 4 + i];
            #pragma unroll
            for (int j = 0; j < 4; ++j) b[j] = Bs[kk][tc * 4 + j];
            #pragma unroll
            for (int i = 0; i < 4; ++i)
                #pragma unroll
                for (int j = 0; j < 4; ++j)
                    acc[i][j] += a[i] * b[j];
        }
        __syncthreads();
    }

    #pragma unroll
    for (int i = 0; i < 4; ++i) {
        int row = m0 + tr * 4 + i;
        #pragma unroll
        for (int j = 0; j < 4; ++j) {
            int col = n0 + tc * 4 + j;
            C[(size_t)row * N + col] = acc[i][j] + bias[col];
        }
    }
}

// ---------------------------------------------------------------------------
// RoPE, applied in place.
// blockIdx.y == 0 -> q buffer [4096][16*64]
// blockIdx.y == 1 -> kv buffer [4096][16*128], k = first 64 of each 128 chunk
// tid = ((row*16)+h)*32 + j, j in [0,32)
// ---------------------------------------------------------------------------
__global__ void rope_kernel(float* __restrict__ q, float* __restrict__ kv)
{
    int tid = blockIdx.x * blockDim.x + threadIdx.x;   // < 4096*16*32 = 2097152
    int j   = tid & 31;
    int h   = (tid >> 5) & 15;
    int row = tid >> 9;                                // b*SEQ + t
    int tpos = row & (SEQ - 1);

    float inv_freq = powf(10000.0f, -(float)(2 * j) / 64.0f);
    float ang = (float)tpos * inv_freq;
    float s, c;
    sincosf(ang, &s, &c);

    float* p;
    if (blockIdx.y == 0) {
        p = q + (size_t)row * D_MODEL + h * 64;
    } else {
        p = kv + (size_t)row * (2 * D_MODEL) + h * 128;
    }
    float x1 = p[j], x2 = p[j + 32];
    p[j]      = x1 * c - x2 * s;
    p[j + 32] = x1 * s + x2 * c;
}

// ---------------------------------------------------------------------------
// memory_kv[b][h][dd] = mean over t of kv[b,t,h,dd], dd in [0,128): k then v
// (kv must already be RoPE'd for the k half)
// ---------------------------------------------------------------------------
__global__ void mean_kv_kernel(const float* __restrict__ kv, float* __restrict__ mem)
{
    int tid = blockIdx.x * blockDim.x + threadIdx.x;
    if (tid >= BATCH * N_HEADS * 128) return;
    int dd = tid & 127;
    int h  = (tid >> 7) & 15;
    int b  = tid >> 11;
    const float* base = kv + ((size_t)b * SEQ * N_HEADS) * 128 + h * 128 + dd;
    float sum = 0.f;
    #pragma unroll 8
    for (int t = 0; t < SEQ; ++t) sum += base[(size_t)t * N_HEADS * 128];
    mem[tid] = sum * (1.0f / SEQ);
}

// ---------------------------------------------------------------------------
// 1-D bias table over dist = q - k in [-(SEQ-1), SEQ-1], index d + SEQ-1
// ---------------------------------------------------------------------------
__global__ void bias_tab_kernel(float* __restrict__ bias_d)
{
    int i = blockIdx.x * blockDim.x + threadIdx.x;
    if (i >= 2 * SEQ - 1) return;
    float d = (float)(i - (SEQ - 1));
    float ls  = -0.1f * logf(fabsf(d) + 1.0f);
    float dec = expf(-fmaxf(d, 0.0f) * 0.01f);
    bias_d[i] = ls + logf(dec + 1e-9f);
}

// ---------------------------------------------------------------------------
// Flash-style attention + fused infini branch.
// grid = (SEQ/256, BATCH*N_HEADS), 256 threads; thread owns one q row.
// q, out layout: [B,T,H,64]; kv layout: [B,T,H,128] (k first 64, v last 64)
// ---------------------------------------------------------------------------
__global__ __launch_bounds__(256) void attn_kernel(
    const float* __restrict__ q, const float* __restrict__ kv,
    const float* __restrict__ bias_d, const float* __restrict__ mem,
    float* __restrict__ out)
{
    __shared__ float Ks[32][64];
    __shared__ float Vs[32][64];
    __shared__ float bias_s[2 * SEQ - 1];

    const int t  = threadIdx.x;
    const int bh = blockIdx.y;           // 0..31
    const int b  = bh >> 4, h = bh & 15;
    const int qi = blockIdx.x * 256 + t; // q row in [0, SEQ)

    // stage bias table (sync happens at top of first k-tile iteration)
    for (int i = t; i < 2 * SEQ - 1; i += 256) bias_s[i] = bias_d[i];

    // q row -> registers
    float qr[64];
    const float* qp = q + ((size_t)(b * SEQ + qi) * N_HEADS + h) * 64;
    #pragma unroll
    for (int i = 0; i < 16; ++i) {
        float4 v4 = *(const float4*)(qp + i * 4);
        qr[i*4+0] = v4.x; qr[i*4+1] = v4.y; qr[i*4+2] = v4.z; qr[i*4+3] = v4.w;
    }

    float o[64] = {};
    float m = -1e30f, l = 0.f;

    for (int k0 = 0; k0 < SEQ; k0 += 32) {
        __syncthreads();   // also covers bias_s staging on first iteration
        #pragma unroll
        for (int i = 0; i < 8; ++i) {
            int idx = t + i * 256;             // 0..2047
            int r = idx >> 6, c = idx & 63;
            const float* kp = kv + ((size_t)(b * SEQ + k0 + r) * N_HEADS + h) * 128;
            Ks[r][c] = kp[c];
            Vs[r][c] = kp[64 + c];
        }
        __syncthreads();

        float sc[32];
        float tile_max = -1e30f;
        #pragma unroll
        for (int j = 0; j < 32; ++j) {
            float dot = 0.f;
            #pragma unroll
            for (int d = 0; d < 64; ++d) dot += qr[d] * Ks[j][d];
            float s = dot * 0.125f + bias_s[qi - (k0 + j) + (SEQ - 1)];
            sc[j] = s;
            tile_max = fmaxf(tile_max, s);
        }
        float m_new = fmaxf(m, tile_max);
        float corr = __expf(m - m_new);
        l *= corr;
        #pragma unroll
        for (int d = 0; d < 64; ++d) o[d] *= corr;
        #pragma unroll
        for (int j = 0; j < 32; ++j) {
            float p = __expf(sc[j] - m_new);
            l += p;
            #pragma unroll
            for (int d = 0; d < 64; ++d) o[d] += p * Vs[j][d];
        }
        m = m_new;
    }

    // infini branch fused: out += 0.2 * sigmoid(q . mem_k) * mem_v
    const float* mkv = mem + (size_t)bh * 128;
    float sdot = 0.f;
    #pragma unroll
    for (int d = 0; d < 64; ++d) sdot += qr[d] * mkv[d];
    float sig = 1.f / (1.f + __expf(-sdot));

    float inv_l = 1.f / l;
    float* op = out + ((size_t)(b * SEQ + qi) * N_HEADS + h) * 64;
    #pragma unroll
    for (int i = 0; i < 16; ++i) {
        float4 v4;
        v4.x = o[i*4+0] * inv_l + 0.2f * sig * mkv[64 + i*4+0];
        v4.y = o[i*4+1] * inv_l + 0.2f * sig * mkv[64 + i*4+1];
        v4.z = o[i*4+2] * inv_l + 0.2f * sig * mkv[64 + i*4+2];
        v4.w = o[i*4+3] * inv_l + 0.2f * sig * mkv[64 + i*4+3];
        *(float4*)(op + i * 4) = v4;
    }
}

// ---------------------------------------------------------------------------
extern "C" void kernel_launch(void* const* d_in, const int* in_sizes, int n_in,
                              void* d_out, int out_size, void* d_ws, size_t ws_size,
                              hipStream_t stream)
{
    const float* x        = (const float*)d_in[0];
    const float* Wq       = (const float*)d_in[1];
    const float* bq       = (const float*)d_in[2];
    const float* Wkv_down = (const float*)d_in[3];
    const float* bkv_down = (const float*)d_in[4];
    const float* Wkv_up   = (const float*)d_in[5];
    const float* bkv_up   = (const float*)d_in[6];
    const float* Wo       = (const float*)d_in[7];
    const float* bo       = (const float*)d_in[8];
    float* out = (float*)d_out;

    // Workspace layout (floats)
    float* ws = (float*)d_ws;
    float* q_buf    = ws;                          // 4096*1024  = 4194304
    float* kvd_buf  = q_buf   + 4194304;           // 4096*256   = 1048576
    float* kv_buf   = kvd_buf + 1048576;           // 4096*2048  = 8388608
    float* ao_buf   = kv_buf  + 8388608;           // 4096*1024  = 4194304
    float* bias_buf = ao_buf  + 4194304;           // 4095 (pad to 4096)
    float* mem_buf  = bias_buf + 4096;             // 2*16*128   = 4096
    // total = 17833984 floats = 71.3 MB

    dim3 blk(256);

    // 1) q = x @ Wq + bq
    gemm_f32<<<dim3(D_MODEL / 64, M_ROWS / 64), blk, 0, stream>>>(
        x, Wq, bq, q_buf, M_ROWS, D_MODEL, D_MODEL);
    // 2) kvd = x @ Wkv_down + bkv_down
    gemm_f32<<<dim3(D_LATENT / 64, M_ROWS / 64), blk, 0, stream>>>(
        x, Wkv_down, bkv_down, kvd_buf, M_ROWS, D_LATENT, D_MODEL);
    // 3) kv = kvd @ Wkv_up + bkv_up
    gemm_f32<<<dim3(2 * D_MODEL / 64, M_ROWS / 64), blk, 0, stream>>>(
        kvd_buf, Wkv_up, bkv_up, kv_buf, M_ROWS, 2 * D_MODEL, D_LATENT);
    // 4) RoPE in place on q and k-half of kv
    rope_kernel<<<dim3((M_ROWS * N_HEADS * 32) / 256, 2), blk, 0, stream>>>(q_buf, kv_buf);
    // 5) memory k/v means (post-RoPE)
    mean_kv_kernel<<<dim3((BATCH * N_HEADS * 128 + 255) / 256), blk, 0, stream>>>(kv_buf, mem_buf);
    // 6) bias table
    bias_tab_kernel<<<dim3((2 * SEQ - 1 + 255) / 256), blk, 0, stream>>>(bias_buf);
    // 7) attention + infini
    attn_kernel<<<dim3(SEQ / 256, BATCH * N_HEADS), blk, 0, stream>>>(
        q_buf, kv_buf, bias_buf, mem_buf, ao_buf);
    // 8) out = ao @ Wo + bo
    gemm_f32<<<dim3(D_MODEL / 64, M_ROWS / 64), blk, 0, stream>>>(
        ao_buf, Wo, bo, out, M_ROWS, D_MODEL, D_MODEL);
}

// Round 3
// 351.732 us; speedup vs baseline: 8.4711x; 8.4711x over previous
//
#include <hip/hip_runtime.h>
#include <hip/hip_bf16.h>

#define D_MODEL 1024
#define N_HEADS 16
#define HEAD_DIM 64
#define D_LATENT 256
#define BATCH 2
#define SEQ 2048
#define M_ROWS (BATCH * SEQ)   // 4096

typedef __bf16 bf16;
typedef __attribute__((ext_vector_type(8))) __bf16 bf16x8;
typedef __attribute__((ext_vector_type(4))) float f32x4;

#define MFMA_BF16(a, b, c) __builtin_amdgcn_mfma_f32_16x16x32_bf16((a), (b), (c), 0, 0, 0)

__device__ __forceinline__ void gll16(const void* g, void* l) {
    __builtin_amdgcn_global_load_lds(
        (const __attribute__((address_space(1))) unsigned int*)g,
        (__attribute__((address_space(3))) unsigned int*)l, 16, 0, 0);
}

// ---------------------------------------------------------------------------
// f32 -> bf16 convert (8 elems/thread, 16B stores)
// ---------------------------------------------------------------------------
__global__ void convert_bf16x8(const float* __restrict__ src, bf16* __restrict__ dst, int n8)
{
    int i = blockIdx.x * 256 + threadIdx.x;
    if (i >= n8) return;
    const float4* s = ((const float4*)src) + (size_t)i * 2;
    float4 a = s[0], b = s[1];
    bf16x8 v;
    v[0] = (bf16)a.x; v[1] = (bf16)a.y; v[2] = (bf16)a.z; v[3] = (bf16)a.w;
    v[4] = (bf16)b.x; v[5] = (bf16)b.y; v[6] = (bf16)b.z; v[7] = (bf16)b.w;
    *(bf16x8*)(dst + (size_t)i * 8) = v;
}

// ---------------------------------------------------------------------------
// W [K][N] f32  ->  Wt [N][K] bf16   (tiled transpose)
// ---------------------------------------------------------------------------
__global__ __launch_bounds__(256) void transpose_w(
    const float* __restrict__ W, bf16* __restrict__ Wt, int K, int N)
{
    __shared__ float tw[32][33];
    int n0 = blockIdx.x * 32, k0 = blockIdx.y * 32;
    int c = threadIdx.x & 31, r = threadIdx.x >> 5;   // r: 0..7
    #pragma unroll
    for (int it = 0; it < 4; ++it)
        tw[r + it * 8][c] = W[(size_t)(k0 + r + it * 8) * N + n0 + c];
    __syncthreads();
    #pragma unroll
    for (int it = 0; it < 4; ++it)
        Wt[(size_t)(n0 + r + it * 8) * K + k0 + c] = (bf16)tw[c][r + it * 8];
}

// ---------------------------------------------------------------------------
// bf16 MFMA GEMM: C[M,N] = A[M,K] @ Bt[N,K]^T + bias
// 128x128 tile, BK=32, 4 waves; global_load_lds(16B) staging with
// source-side swizzle (G21), swizzled ds_read_b128 fragment loads.
// OUT_BF16: 1 -> bf16 C, 0 -> f32 C.
// ---------------------------------------------------------------------------
template<int OUT_BF16>
__global__ __launch_bounds__(256) void gemm_bf16(
    const bf16* __restrict__ A,    // [M][K]
    const bf16* __restrict__ Bt,   // [N][K]
    const float* __restrict__ bias,
    void* __restrict__ C,
    int M, int N, int K)
{
    __shared__ bf16 As[128 * 32];
    __shared__ bf16 Bs[128 * 32];
    const int tid = threadIdx.x;
    const int lane = tid & 63;
    const int w = tid >> 6;
    const int wr = w >> 1, wc = w & 1;
    const int l15 = lane & 15, lh = lane >> 4;
    const int m0 = blockIdx.y * 128, n0 = blockIdx.x * 128;

    f32x4 acc[4][4] = {};

    for (int k0 = 0; k0 < K; k0 += 32) {
        __syncthreads();
        #pragma unroll
        for (int it = 0; it < 2; ++it) {
            int c = it * 256 + tid;          // 0..511
            int row = c >> 2, part = c & 3;  // rows 0..127, 4x 16B parts (64B rows)
            int p = part ^ ((row >> 1) & 3); // source pre-swizzle
            gll16(A  + (size_t)(m0 + row) * K + k0 + p * 8, As + c * 8);
            gll16(Bt + (size_t)(n0 + row) * K + k0 + p * 8, Bs + c * 8);
        }
        __syncthreads();

        bf16x8 af[4], bg[4];
        #pragma unroll
        for (int i = 0; i < 4; ++i) {
            int row = wr * 64 + i * 16 + l15;
            int cc = lh ^ ((row >> 1) & 3);
            af[i] = *(const bf16x8*)(As + row * 32 + cc * 8);
        }
        #pragma unroll
        for (int j = 0; j < 4; ++j) {
            int row = wc * 64 + j * 16 + l15;
            int cc = lh ^ ((row >> 1) & 3);
            bg[j] = *(const bf16x8*)(Bs + row * 32 + cc * 8);
        }
        #pragma unroll
        for (int i = 0; i < 4; ++i)
            #pragma unroll
            for (int j = 0; j < 4; ++j)
                acc[i][j] = MFMA_BF16(af[i], bg[j], acc[i][j]);
    }

    #pragma unroll
    for (int i = 0; i < 4; ++i) {
        int row = m0 + wr * 64 + i * 16 + lh * 4;
        #pragma unroll
        for (int j = 0; j < 4; ++j) {
            int col = n0 + wc * 64 + j * 16 + l15;
            float bv = bias[col];
            #pragma unroll
            for (int r = 0; r < 4; ++r) {
                float v = acc[i][j][r] + bv;
                if (OUT_BF16) ((bf16*)C)[(size_t)(row + r) * N + col] = (bf16)v;
                else          ((float*)C)[(size_t)(row + r) * N + col] = v;
            }
        }
    }
}

// ---------------------------------------------------------------------------
// RoPE + pack to head-major bf16.  q_f [4096][1024] -> Qh [BH][T][64]
// ---------------------------------------------------------------------------
__global__ void rope_pack_q(const float* __restrict__ q_f, bf16* __restrict__ Qh)
{
    int tid = blockIdx.x * 256 + threadIdx.x;  // < 4096*16*32
    int j = tid & 31, h = (tid >> 5) & 15, row = tid >> 9;
    int tpos = row & (SEQ - 1), b = row >> 11;
    float inv_freq = exp2f((float)j * -0.4152410118609203f);  // 2^(-j*2*log2(1e4)/64)
    float ang = (float)tpos * inv_freq;
    float sn, cs; sincosf(ang, &sn, &cs);
    const float* p = q_f + (size_t)row * D_MODEL + h * 64;
    float x1 = p[j], x2 = p[j + 32];
    bf16* o = Qh + ((size_t)(b * N_HEADS + h) * SEQ + tpos) * 64;
    o[j]      = (bf16)(x1 * cs - x2 * sn);
    o[j + 32] = (bf16)(x1 * sn + x2 * cs);
}

// kv_f [4096][2048] (k = first 64 of each 128-chunk) -> Kh [BH][T][64]
__global__ void rope_pack_k(const float* __restrict__ kv_f, bf16* __restrict__ Kh)
{
    int tid = blockIdx.x * 256 + threadIdx.x;
    int j = tid & 31, h = (tid >> 5) & 15, row = tid >> 9;
    int tpos = row & (SEQ - 1), b = row >> 11;
    float inv_freq = exp2f((float)j * -0.4152410118609203f);
    float ang = (float)tpos * inv_freq;
    float sn, cs; sincosf(ang, &sn, &cs);
    const float* p = kv_f + (size_t)row * (2 * D_MODEL) + h * 128;
    float x1 = p[j], x2 = p[j + 32];
    bf16* o = Kh + ((size_t)(b * N_HEADS + h) * SEQ + tpos) * 64;
    o[j]      = (bf16)(x1 * cs - x2 * sn);
    o[j + 32] = (bf16)(x1 * sn + x2 * cs);
}

// ---------------------------------------------------------------------------
// v-half of kv_f -> Vt [BH][64][T]  (d-major, for PV B-fragments)
// ---------------------------------------------------------------------------
__global__ __launch_bounds__(256) void transpose_v(
    const float* __restrict__ kv_f, bf16* __restrict__ Vt)
{
    __shared__ bf16 tile[64][80];
    int blk = blockIdx.x;        // bh*32 + tt
    int tt = blk & 31, bh = blk >> 5;
    int b = bh >> 4, h = bh & 15;
    int t0 = tt * 64;
    #pragma unroll
    for (int it = 0; it < 16; ++it) {
        int lin = it * 256 + threadIdx.x;
        int r = lin >> 6, d = lin & 63;
        float v = kv_f[(size_t)(b * SEQ + t0 + r) * (2 * D_MODEL) + h * 128 + 64 + d];
        tile[d][r] = (bf16)v;
    }
    __syncthreads();
    #pragma unroll
    for (int it = 0; it < 2; ++it) {
        int lin = it * 256 + threadIdx.x;
        int d = lin >> 3, seg = lin & 7;
        bf16x8 v = *(const bf16x8*)(&tile[d][seg * 8]);
        *(bf16x8*)(Vt + ((size_t)(bh * 64 + d)) * SEQ + t0 + seg * 8) = v;
    }
}

// ---------------------------------------------------------------------------
// memory k/v means: mem[bh][0:64] = mean_t Kh, mem[bh][64:128] = mean_t v
// ---------------------------------------------------------------------------
__global__ __launch_bounds__(256) void mean_kv(
    const bf16* __restrict__ Kh, const float* __restrict__ kv_f,
    float* __restrict__ memkv)
{
    __shared__ float red[4][64];
    int bh = blockIdx.x;
    int b = bh >> 4, h = bh & 15;
    int tid = threadIdx.x;
    int d = tid & 63, rg = tid >> 6;
    float s = 0.f;
    for (int t = rg * 512; t < rg * 512 + 512; ++t)
        s += (float)Kh[((size_t)bh * SEQ + t) * 64 + d];
    red[rg][d] = s;
    __syncthreads();
    if (tid < 64)
        memkv[bh * 128 + tid] =
            (red[0][tid] + red[1][tid] + red[2][tid] + red[3][tid]) * (1.f / SEQ);
    __syncthreads();
    s = 0.f;
    for (int t = rg * 512; t < rg * 512 + 512; ++t)
        s += kv_f[(size_t)(b * SEQ + t) * (2 * D_MODEL) + h * 128 + 64 + d];
    red[rg][d] = s;
    __syncthreads();
    if (tid < 64)
        memkv[bh * 128 + 64 + tid] =
            (red[0][tid] + red[1][tid] + red[2][tid] + red[3][tid]) * (1.f / SEQ);
}

// ---------------------------------------------------------------------------
// dist-bias table: idx = (q - k) + 2047
// ---------------------------------------------------------------------------
__global__ void bias_tab_kernel(float* __restrict__ bias_d)
{
    int i = blockIdx.x * 256 + threadIdx.x;
    if (i >= 2 * SEQ - 1) return;
    float d = (float)(i - (SEQ - 1));
    float ls  = -0.1f * logf(fabsf(d) + 1.0f);
    float dec = expf(-fmaxf(d, 0.0f) * 0.01f);
    bias_d[i] = ls + logf(dec + 1e-9f);
}

// ---------------------------------------------------------------------------
// MFMA flash attention + fused infini.
// grid = (SEQ/128, B*H), 256 threads (4 waves, 32 q-rows each), KVBLK=64.
// ---------------------------------------------------------------------------
__global__ __launch_bounds__(256) void attn_mfma(
    const bf16* __restrict__ Qh,   // [BH][T][64]
    const bf16* __restrict__ Kh,   // [BH][T][64]
    const bf16* __restrict__ Vt,   // [BH][64][T]
    const float* __restrict__ bias_d, // [4095]
    const float* __restrict__ memkv,  // [BH][128]
    bf16* __restrict__ ao)            // [B][T][H][64]
{
    __shared__ bf16 Qs[128 * 64];      // 16 KB, linear (read once)
    __shared__ bf16 Ks[64 * 64];       // 8 KB, swizzled
    __shared__ bf16 Vs[64 * 64];       // 8 KB, swizzled ([d][kv])
    __shared__ bf16 Ps[4][32 * 88];    // 22 KB, per-wave P, padded rows
    __shared__ float bias_s[2176];     // 8.5 KB staged window
    // total 63.9 KB

    const int tid = threadIdx.x;
    const int lane = tid & 63;
    const int w = tid >> 6;
    const int l15 = lane & 15, lh = lane >> 4;
    const int bh = blockIdx.y;
    const int q0 = blockIdx.x * 128;
    const size_t bhT = (size_t)bh * SEQ;

    // bias window: block touches idx in [q0, q0+2174]
    for (int i = tid; i < 2175; i += 256) bias_s[i] = bias_d[q0 + i];
    // Q tile (contiguous 16 KB)
    #pragma unroll
    for (int it = 0; it < 4; ++it) {
        int c = it * 256 + tid;
        gll16(Qh + (bhT + q0) * 64 + c * 8, Qs + c * 8);
    }
    __syncthreads();

    bf16x8 qf[2][2];
    #pragma unroll
    for (int i = 0; i < 2; ++i)
        #pragma unroll
        for (int ks = 0; ks < 2; ++ks)
            qf[i][ks] = *(const bf16x8*)(Qs + (w * 32 + i * 16 + l15) * 64 + ks * 32 + lh * 8);

    f32x4 o[2][4] = {};
    float mreg[2][4], lreg[2][4];
    #pragma unroll
    for (int i = 0; i < 2; ++i)
        #pragma unroll
        for (int r = 0; r < 4; ++r) { mreg[i][r] = -1e30f; lreg[i][r] = 0.f; }

    for (int kt = 0; kt < SEQ / 64; ++kt) {
        __syncthreads();
        #pragma unroll
        for (int it = 0; it < 2; ++it) {
            int c = it * 256 + tid;          // 0..511
            int row = c >> 3, part = c & 7;  // 64 rows x 8 parts (128B rows)
            int p = part ^ (row & 7);        // source pre-swizzle
            gll16(Kh + (bhT + kt * 64 + row) * 64 + p * 8, Ks + c * 8);
            gll16(Vt + ((size_t)(bh * 64 + row)) * SEQ + kt * 64 + p * 8, Vs + c * 8);
        }
        __syncthreads();

        // S = Q K^T
        f32x4 s_[2][4] = {};
        #pragma unroll
        for (int ks = 0; ks < 2; ++ks) {
            bf16x8 kf[4];
            #pragma unroll
            for (int jk = 0; jk < 4; ++jk) {
                int row = jk * 16 + l15;
                int cc = (ks * 4 + lh) ^ (row & 7);
                kf[jk] = *(const bf16x8*)(Ks + row * 64 + cc * 8);
            }
            #pragma unroll
            for (int i = 0; i < 2; ++i)
                #pragma unroll
                for (int jk = 0; jk < 4; ++jk)
                    s_[i][jk] = MFMA_BF16(qf[i][ks], kf[jk], s_[i][jk]);
        }

        // bias + online softmax (row owner: 16-lane group, row = lh*4+r (+i*16))
        float p_[2][4][4];
        #pragma unroll
        for (int i = 0; i < 2; ++i) {
            #pragma unroll
            for (int r = 0; r < 4; ++r) {
                int qrel = w * 32 + i * 16 + lh * 4 + r;  // q - q0
                float mx = -1e30f;
                #pragma unroll
                for (int jk = 0; jk < 4; ++jk) {
                    int ki = kt * 64 + jk * 16 + l15;
                    float v = s_[i][jk][r] * 0.125f + bias_s[qrel - ki + (SEQ - 1)];
                    p_[i][jk][r] = v;
                    mx = fmaxf(mx, v);
                }
                #pragma unroll
                for (int dd = 1; dd < 16; dd <<= 1) mx = fmaxf(mx, __shfl_xor(mx, dd, 64));
                float mn = fmaxf(mreg[i][r], mx);
                float corr = __expf(mreg[i][r] - mn);
                mreg[i][r] = mn;
                float sum = 0.f;
                #pragma unroll
                for (int jk = 0; jk < 4; ++jk) {
                    float e = __expf(p_[i][jk][r] - mn);
                    p_[i][jk][r] = e;
                    sum += e;
                }
                #pragma unroll
                for (int dd = 1; dd < 16; dd <<= 1) sum += __shfl_xor(sum, dd, 64);
                lreg[i][r] = lreg[i][r] * corr + sum;
                #pragma unroll
                for (int jd = 0; jd < 4; ++jd) o[i][jd][r] *= corr;
            }
        }

        // P -> LDS (bf16), per-wave region, padded rows (88)
        #pragma unroll
        for (int i = 0; i < 2; ++i)
            #pragma unroll
            for (int jk = 0; jk < 4; ++jk)
                #pragma unroll
                for (int r = 0; r < 4; ++r) {
                    int q = i * 16 + lh * 4 + r;
                    int kv = jk * 16 + l15;
                    Ps[w][q * 88 + kv] = (bf16)p_[i][jk][r];
                }

        // O += P V
        #pragma unroll
        for (int ks = 0; ks < 2; ++ks) {
            bf16x8 pf[2], vf[4];
            #pragma unroll
            for (int i = 0; i < 2; ++i)
                pf[i] = *(const bf16x8*)(&Ps[w][(i * 16 + l15) * 88 + ks * 32 + lh * 8]);
            #pragma unroll
            for (int jd = 0; jd < 4; ++jd) {
                int row = jd * 16 + l15;
                int cc = (ks * 4 + lh) ^ (row & 7);
                vf[jd] = *(const bf16x8*)(Vs + row * 64 + cc * 8);
            }
            #pragma unroll
            for (int i = 0; i < 2; ++i)
                #pragma unroll
                for (int jd = 0; jd < 4; ++jd)
                    o[i][jd] = MFMA_BF16(pf[i], vf[jd], o[i][jd]);
        }
    }

    // epilogue: infini + normalize + store
    const float* mk = memkv + bh * 128;
    const int b = bh >> 4, h = bh & 15;
    #pragma unroll
    for (int i = 0; i < 2; ++i) {
        float sig[4];
        #pragma unroll
        for (int r = 0; r < 4; ++r) {
            int qrow = w * 32 + i * 16 + lh * 4 + r;
            float dot = 0.f;
            #pragma unroll
            for (int dd = 0; dd < 4; ++dd) {
                int d = l15 + dd * 16;
                dot += (float)Qs[qrow * 64 + d] * mk[d];
            }
            #pragma unroll
            for (int d2 = 1; d2 < 16; d2 <<= 1) dot += __shfl_xor(dot, d2, 64);
            sig[r] = 1.f / (1.f + __expf(-dot));
        }
        #pragma unroll
        for (int jd = 0; jd < 4; ++jd) {
            int d = jd * 16 + l15;
            float mv = mk[64 + d];
            #pragma unroll
            for (int r = 0; r < 4; ++r) {
                int qi = q0 + w * 32 + i * 16 + lh * 4 + r;
                float val = o[i][jd][r] / lreg[i][r] + 0.2f * sig[r] * mv;
                ao[((size_t)(b * SEQ + qi)) * D_MODEL + h * 64 + d] = (bf16)val;
            }
        }
    }
}

// ---------------------------------------------------------------------------
extern "C" void kernel_launch(void* const* d_in, const int* in_sizes, int n_in,
                              void* d_out, int out_size, void* d_ws, size_t ws_size,
                              hipStream_t stream)
{
    const float* x        = (const float*)d_in[0];
    const float* Wq       = (const float*)d_in[1];
    const float* bq       = (const float*)d_in[2];
    const float* Wkv_down = (const float*)d_in[3];
    const float* bkv_down = (const float*)d_in[4];
    const float* Wkv_up   = (const float*)d_in[5];
    const float* bkv_up   = (const float*)d_in[6];
    const float* Wo       = (const float*)d_in[7];
    const float* bo       = (const float*)d_in[8];
    float* out = (float*)d_out;

    // workspace layout (bytes)
    char* p = (char*)d_ws;
    bf16* xb    = (bf16*)p;  p += 8388608;    // [4096][1024]; later reused as Qh
    bf16* Wqt   = (bf16*)p;  p += 2097152;    // [1024][1024]
    bf16* Wdt   = (bf16*)p;  p += 524288;     // [256][1024]
    bf16* Wut   = (bf16*)p;  p += 1048576;    // [2048][256]
    bf16* Wot   = (bf16*)p;  p += 2097152;    // [1024][1024]
    float* q_f  = (float*)p; p += 16777216;   // [4096][1024] fp32 = 16 MB exactly
    bf16* kvd_b = (bf16*)p;  p += 2097152;    // [4096][256]
    float* kv_f = (float*)p; p += 33554432;   // [4096][2048]
    bf16* VtB   = (bf16*)p;  p += 8388608;    // [32][64][2048]
    float* memb = (float*)p; p += 16384;      // [32][128]
    float* bias_d = (float*)p; p += 16384;    // [4095]
    // aliases (lifetimes: src buffer fully dead before alias written)
    bf16* Qh = xb;                                   // xb dead after kv-down GEMM
    bf16* ao = (bf16*)q_f;                           // lower 8 MB of q_f region
    bf16* Kh = (bf16*)((char*)q_f + 8388608);        // upper 8 MB of q_f region (FIXED)

    dim3 blk(256);

    // 1) bf16 conversions / weight transposes
    convert_bf16x8<<<dim3((M_ROWS * D_MODEL / 8 + 255) / 256), blk, 0, stream>>>(x, xb, M_ROWS * D_MODEL / 8);
    transpose_w<<<dim3(D_MODEL / 32, D_MODEL / 32), blk, 0, stream>>>(Wq, Wqt, D_MODEL, D_MODEL);
    transpose_w<<<dim3(D_LATENT / 32, D_MODEL / 32), blk, 0, stream>>>(Wkv_down, Wdt, D_MODEL, D_LATENT);
    transpose_w<<<dim3(2 * D_MODEL / 32, D_LATENT / 32), blk, 0, stream>>>(Wkv_up, Wut, D_LATENT, 2 * D_MODEL);
    transpose_w<<<dim3(D_MODEL / 32, D_MODEL / 32), blk, 0, stream>>>(Wo, Wot, D_MODEL, D_MODEL);

    // 2) projections
    gemm_bf16<0><<<dim3(D_MODEL / 128, M_ROWS / 128), blk, 0, stream>>>(
        xb, Wqt, bq, q_f, M_ROWS, D_MODEL, D_MODEL);
    gemm_bf16<1><<<dim3(D_LATENT / 128, M_ROWS / 128), blk, 0, stream>>>(
        xb, Wdt, bkv_down, kvd_b, M_ROWS, D_LATENT, D_MODEL);
    gemm_bf16<0><<<dim3(2 * D_MODEL / 128, M_ROWS / 128), blk, 0, stream>>>(
        kvd_b, Wut, bkv_up, kv_f, M_ROWS, 2 * D_MODEL, D_LATENT);

    // 3) RoPE + packing (q_f/kv_f fp32 -> single bf16 rounding)
    rope_pack_q<<<dim3(M_ROWS * N_HEADS * 32 / 256), blk, 0, stream>>>(q_f, Qh);
    rope_pack_k<<<dim3(M_ROWS * N_HEADS * 32 / 256), blk, 0, stream>>>(kv_f, Kh);
    transpose_v<<<dim3(BATCH * N_HEADS * (SEQ / 64)), blk, 0, stream>>>(kv_f, VtB);

    // 4) memory means + bias table
    mean_kv<<<dim3(BATCH * N_HEADS), blk, 0, stream>>>(Kh, kv_f, memb);
    bias_tab_kernel<<<dim3((2 * SEQ - 1 + 255) / 256), blk, 0, stream>>>(bias_d);

    // 5) attention (+infini fused)
    attn_mfma<<<dim3(SEQ / 128, BATCH * N_HEADS), blk, 0, stream>>>(
        Qh, Kh, VtB, bias_d, memb, ao);

    // 6) output projection
    gemm_bf16<0><<<dim3(D_MODEL / 128, M_ROWS / 128), blk, 0, stream>>>(
        ao, Wot, bo, out, M_ROWS, D_MODEL, D_MODEL);
}

// Round 5
// 282.964 us; speedup vs baseline: 10.5299x; 1.2430x over previous
//
#include <hip/hip_runtime.h>
#include <hip/hip_bf16.h>

#define D_MODEL 1024
#define N_HEADS 16
#define HEAD_DIM 64
#define D_LATENT 256
#define BATCH 2
#define SEQ 2048
#define M_ROWS (BATCH * SEQ)   // 4096

typedef __bf16 bf16;
typedef __attribute__((ext_vector_type(8))) __bf16 bf16x8;
typedef __attribute__((ext_vector_type(4))) float f32x4;

#define MFMA_BF16(a, b, c) __builtin_amdgcn_mfma_f32_16x16x32_bf16((a), (b), (c), 0, 0, 0)
#define LOG2E 1.4426950408889634f

__device__ __forceinline__ void gll16(const void* g, void* l) {
    __builtin_amdgcn_global_load_lds(
        (const __attribute__((address_space(1))) unsigned int*)g,
        (__attribute__((address_space(3))) unsigned int*)l, 16, 0, 0);
}

// ---------------------------------------------------------------------------
// f32 -> bf16 convert
// ---------------------------------------------------------------------------
__global__ void convert_bf16x8(const float* __restrict__ src, bf16* __restrict__ dst, int n8)
{
    int i = blockIdx.x * 256 + threadIdx.x;
    if (i >= n8) return;
    const float4* s = ((const float4*)src) + (size_t)i * 2;
    float4 a = s[0], b = s[1];
    bf16x8 v;
    v[0] = (bf16)a.x; v[1] = (bf16)a.y; v[2] = (bf16)a.z; v[3] = (bf16)a.w;
    v[4] = (bf16)b.x; v[5] = (bf16)b.y; v[6] = (bf16)b.z; v[7] = (bf16)b.w;
    *(bf16x8*)(dst + (size_t)i * 8) = v;
}

// ---------------------------------------------------------------------------
// W [K][N] f32 -> Wt [N][K] bf16
// ---------------------------------------------------------------------------
__global__ __launch_bounds__(256) void transpose_w(
    const float* __restrict__ W, bf16* __restrict__ Wt, int K, int N)
{
    __shared__ float tw[32][33];
    int n0 = blockIdx.x * 32, k0 = blockIdx.y * 32;
    int c = threadIdx.x & 31, r = threadIdx.x >> 5;
    #pragma unroll
    for (int it = 0; it < 4; ++it)
        tw[r + it * 8][c] = W[(size_t)(k0 + r + it * 8) * N + n0 + c];
    __syncthreads();
    #pragma unroll
    for (int it = 0; it < 4; ++it)
        Wt[(size_t)(n0 + r + it * 8) * K + k0 + c] = (bf16)tw[c][r + it * 8];
}

// ---------------------------------------------------------------------------
// RoPE cos/sin table: rtab[t*32+j] = {cos, sin}(t * 10000^(-2j/64))
// ---------------------------------------------------------------------------
__global__ void rope_tab_kernel(float2* __restrict__ rtab)
{
    int i = blockIdx.x * 256 + threadIdx.x;     // < 65536
    int j = i & 31, t = i >> 5;
    float inv_freq = exp2f((float)j * -0.4152410118609203f);
    float ang = (float)t * inv_freq;
    float sn, cs; sincosf(ang, &sn, &cs);
    rtab[i] = make_float2(cs, sn);
}

// ---------------------------------------------------------------------------
// dist-bias table pre-scaled by log2(e):  idx = (q-k) + 2047
// ---------------------------------------------------------------------------
__global__ void bias_tab_kernel(float* __restrict__ bias2)
{
    int i = blockIdx.x * 256 + threadIdx.x;
    if (i >= 2 * SEQ - 1) return;
    float d = (float)(i - (SEQ - 1));
    float ls  = -0.1f * logf(fabsf(d) + 1.0f);
    float dec = expf(-fmaxf(d, 0.0f) * 0.01f);
    bias2[i] = (ls + logf(dec + 1e-9f)) * LOG2E;
}

// ---------------------------------------------------------------------------
// Shared MFMA GEMM main loop body (128x128 tile, BK=32, 4 waves)
// ---------------------------------------------------------------------------
__device__ __forceinline__ void gemm_body(
    const bf16* __restrict__ A, const bf16* __restrict__ Bt, int K,
    bf16* As, bf16* Bs, f32x4 (&acc)[4][4],
    int m0, int n0, int tid, int l15, int lh, int wr, int wc)
{
    for (int k0 = 0; k0 < K; k0 += 32) {
        __syncthreads();
        #pragma unroll
        for (int it = 0; it < 2; ++it) {
            int c = it * 256 + tid;          // 0..511
            int row = c >> 2, part = c & 3;
            int p = part ^ ((row >> 1) & 3);
            gll16(A  + (size_t)(m0 + row) * K + k0 + p * 8, As + c * 8);
            gll16(Bt + (size_t)(n0 + row) * K + k0 + p * 8, Bs + c * 8);
        }
        __syncthreads();
        bf16x8 af[4], bg[4];
        #pragma unroll
        for (int i = 0; i < 4; ++i) {
            int row = wr * 64 + i * 16 + l15;
            int cc = lh ^ ((row >> 1) & 3);
            af[i] = *(const bf16x8*)(As + row * 32 + cc * 8);
        }
        #pragma unroll
        for (int j = 0; j < 4; ++j) {
            int row = wc * 64 + j * 16 + l15;
            int cc = lh ^ ((row >> 1) & 3);
            bg[j] = *(const bf16x8*)(Bs + row * 32 + cc * 8);
        }
        #pragma unroll
        for (int i = 0; i < 4; ++i)
            #pragma unroll
            for (int j = 0; j < 4; ++j)
                acc[i][j] = MFMA_BF16(af[i], bg[j], acc[i][j]);
    }
}

// ---------------------------------------------------------------------------
// Plain GEMM: C = A @ Bt^T + bias  (OUT_BF16: 1 -> bf16, 0 -> f32)
// ---------------------------------------------------------------------------
template<int OUT_BF16>
__global__ __launch_bounds__(256) void gemm_plain(
    const bf16* __restrict__ A, const bf16* __restrict__ Bt,
    const float* __restrict__ bias, void* __restrict__ C,
    int N, int K)
{
    __shared__ bf16 As[128 * 32];
    __shared__ bf16 Bs[128 * 32];
    const int tid = threadIdx.x, lane = tid & 63, w = tid >> 6;
    const int wr = w >> 1, wc = w & 1;
    const int l15 = lane & 15, lh = lane >> 4;
    const int m0 = blockIdx.y * 128, n0 = blockIdx.x * 128;
    f32x4 acc[4][4] = {};
    gemm_body(A, Bt, K, As, Bs, acc, m0, n0, tid, l15, lh, wr, wc);

    #pragma unroll
    for (int i = 0; i < 4; ++i) {
        int row = m0 + wr * 64 + i * 16 + lh * 4;
        #pragma unroll
        for (int j = 0; j < 4; ++j) {
            int col = n0 + wc * 64 + j * 16 + l15;
            float bv = bias[col];
            #pragma unroll
            for (int r = 0; r < 4; ++r) {
                float v = acc[i][j][r] + bv;
                if (OUT_BF16) ((bf16*)C)[(size_t)(row + r) * N + col] = (bf16)v;
                else          ((float*)C)[(size_t)(row + r) * N + col] = v;
            }
        }
    }
}

// ---------------------------------------------------------------------------
// Q-proj GEMM with fused RoPE + head-major pack.  N=1024, K=1024.
// Out: Qh [BH][T][64] bf16.  Tile cols 128 = heads (2bx, 2bx+1); wc -> head.
// ---------------------------------------------------------------------------
__global__ __launch_bounds__(256) void gemm_q_rope(
    const bf16* __restrict__ A, const bf16* __restrict__ Bt,
    const float* __restrict__ bias, const float2* __restrict__ rtab,
    bf16* __restrict__ Qh)
{
    __shared__ bf16 As[128 * 32];
    __shared__ bf16 Bs[128 * 32];
    const int tid = threadIdx.x, lane = tid & 63, w = tid >> 6;
    const int wr = w >> 1, wc = w & 1;
    const int l15 = lane & 15, lh = lane >> 4;
    const int m0 = blockIdx.y * 128, n0 = blockIdx.x * 128;
    f32x4 acc[4][4] = {};
    gemm_body(A, Bt, D_MODEL, As, Bs, acc, m0, n0, tid, l15, lh, wr, wc);

    const int head = blockIdx.x * 2 + wc;
    #pragma unroll
    for (int i = 0; i < 4; ++i) {
        #pragma unroll
        for (int r = 0; r < 4; ++r) {
            int m = m0 + wr * 64 + i * 16 + lh * 4 + r;
            int tpos = m & (SEQ - 1), b = m >> 11;
            bf16* orow = Qh + ((size_t)(b * N_HEADS + head) * SEQ + tpos) * 64;
            #pragma unroll
            for (int j01 = 0; j01 < 2; ++j01) {
                int jj = j01 * 16 + l15;
                float2 cssn = rtab[tpos * 32 + jj];
                float v1 = acc[i][j01][r]     + bias[head * 64 + jj];
                float v2 = acc[i][j01 + 2][r] + bias[head * 64 + jj + 32];
                orow[jj]      = (bf16)(v1 * cssn.x - v2 * cssn.y);
                orow[jj + 32] = (bf16)(v1 * cssn.y + v2 * cssn.x);
            }
        }
    }
}

// ---------------------------------------------------------------------------
// KV-up GEMM with fused RoPE(k) + pack.  N=2048, K=256.
// Tile cols 128 = one head: wc=0 -> k (RoPE -> Kh), wc=1 -> v (-> Vh).
// ---------------------------------------------------------------------------
__global__ __launch_bounds__(256) void gemm_kv_rope(
    const bf16* __restrict__ A, const bf16* __restrict__ Bt,
    const float* __restrict__ bias, const float2* __restrict__ rtab,
    bf16* __restrict__ Kh, bf16* __restrict__ Vh)
{
    __shared__ bf16 As[128 * 32];
    __shared__ bf16 Bs[128 * 32];
    const int tid = threadIdx.x, lane = tid & 63, w = tid >> 6;
    const int wr = w >> 1, wc = w & 1;
    const int l15 = lane & 15, lh = lane >> 4;
    const int m0 = blockIdx.y * 128, n0 = blockIdx.x * 128;
    f32x4 acc[4][4] = {};
    gemm_body(A, Bt, D_LATENT, As, Bs, acc, m0, n0, tid, l15, lh, wr, wc);

    const int head = blockIdx.x;
    if (wc == 0) {
        #pragma unroll
        for (int i = 0; i < 4; ++i) {
            #pragma unroll
            for (int r = 0; r < 4; ++r) {
                int m = m0 + wr * 64 + i * 16 + lh * 4 + r;
                int tpos = m & (SEQ - 1), b = m >> 11;
                bf16* orow = Kh + ((size_t)(b * N_HEADS + head) * SEQ + tpos) * 64;
                #pragma unroll
                for (int j01 = 0; j01 < 2; ++j01) {
                    int jj = j01 * 16 + l15;
                    float2 cssn = rtab[tpos * 32 + jj];
                    float v1 = acc[i][j01][r]     + bias[head * 128 + jj];
                    float v2 = acc[i][j01 + 2][r] + bias[head * 128 + jj + 32];
                    orow[jj]      = (bf16)(v1 * cssn.x - v2 * cssn.y);
                    orow[jj + 32] = (bf16)(v1 * cssn.y + v2 * cssn.x);
                }
            }
        }
    } else {
        #pragma unroll
        for (int i = 0; i < 4; ++i) {
            #pragma unroll
            for (int r = 0; r < 4; ++r) {
                int m = m0 + wr * 64 + i * 16 + lh * 4 + r;
                int tpos = m & (SEQ - 1), b = m >> 11;
                bf16* orow = Vh + ((size_t)(b * N_HEADS + head) * SEQ + tpos) * 64;
                #pragma unroll
                for (int j = 0; j < 4; ++j) {
                    int d = j * 16 + l15;
                    orow[d] = (bf16)(acc[i][j][r] + bias[head * 128 + 64 + d]);
                }
            }
        }
    }
}

// ---------------------------------------------------------------------------
// Vh [BH][T][64] -> Vt [BH][64][T]  (bf16 -> bf16 tiled transpose)
// ---------------------------------------------------------------------------
__global__ __launch_bounds__(256) void transpose_v_b(
    const bf16* __restrict__ Vh, bf16* __restrict__ Vt)
{
    __shared__ bf16 tile[64][72];
    int blk = blockIdx.x;          // bh*32 + tt
    int tt = blk & 31, bh = blk >> 5;
    int t0 = tt * 64;
    int tid = threadIdx.x;
    #pragma unroll
    for (int it = 0; it < 2; ++it) {
        int lin = it * 256 + tid;
        int r = lin >> 3, c8 = (lin & 7) * 8;
        bf16x8 v = *(const bf16x8*)(Vh + ((size_t)bh * SEQ + t0 + r) * 64 + c8);
        #pragma unroll
        for (int e = 0; e < 8; ++e) tile[c8 + e][r] = v[e];
    }
    __syncthreads();
    #pragma unroll
    for (int it = 0; it < 2; ++it) {
        int lin = it * 256 + tid;
        int d = lin >> 3, seg = (lin & 7) * 8;
        bf16x8 v = *(const bf16x8*)(&tile[d][seg]);
        *(bf16x8*)(Vt + ((size_t)bh * 64 + d) * SEQ + t0 + seg) = v;
    }
}

// ---------------------------------------------------------------------------
// memory means from bf16 Kh (rope'd) and Vh
// ---------------------------------------------------------------------------
__global__ __launch_bounds__(256) void mean_kv(
    const bf16* __restrict__ Kh, const bf16* __restrict__ Vh,
    float* __restrict__ memkv)
{
    __shared__ float red[4][64];
    int bh = blockIdx.x, tid = threadIdx.x;
    int d = tid & 63, rg = tid >> 6;
    float s = 0.f;
    for (int t = rg * 512; t < rg * 512 + 512; ++t)
        s += (float)Kh[((size_t)bh * SEQ + t) * 64 + d];
    red[rg][d] = s;
    __syncthreads();
    if (tid < 64)
        memkv[bh * 128 + tid] =
            (red[0][tid] + red[1][tid] + red[2][tid] + red[3][tid]) * (1.f / SEQ);
    __syncthreads();
    s = 0.f;
    for (int t = rg * 512; t < rg * 512 + 512; ++t)
        s += (float)Vh[((size_t)bh * SEQ + t) * 64 + d];
    red[rg][d] = s;
    __syncthreads();
    if (tid < 64)
        memkv[bh * 128 + 64 + tid] =
            (red[0][tid] + red[1][tid] + red[2][tid] + red[3][tid]) * (1.f / SEQ);
}

// ---------------------------------------------------------------------------
// MFMA flash attention, no-max softmax, fused infini.
// grid = (SEQ/64, B*H), 256 threads (4 waves x 16 q-rows), KVBLK=64.
// LDS 36 KB -> 4 blocks/CU.
// ---------------------------------------------------------------------------
__global__ __launch_bounds__(256) void attn_mfma(
    const bf16* __restrict__ Qh,     // [BH][T][64]
    const bf16* __restrict__ Kh,     // [BH][T][64]
    const bf16* __restrict__ Vt,     // [BH][64][T]
    const float* __restrict__ bias2, // [4095], pre-scaled by log2e
    const float* __restrict__ memkv, // [BH][128]
    bf16* __restrict__ ao)           // [B][T][H][64]
{
    __shared__ bf16 PQ[4 * 16 * 88];   // 11264 B: Q tile (8 KB) then per-wave P
    __shared__ bf16 Ks[64 * 64];       // 8 KB, swizzled
    __shared__ bf16 Vs[64 * 64];       // 8 KB, swizzled [d][kv]
    __shared__ float bias_s[2112];     // 8.4 KB window
    // total ~36 KB

    const int tid = threadIdx.x;
    const int lane = tid & 63;
    const int w = tid >> 6;
    const int l15 = lane & 15, lh = lane >> 4;
    const int bh = blockIdx.y;
    const int q0 = blockIdx.x * 64;
    const size_t bhT = (size_t)bh * SEQ;

    // local bias idx = qrel - ki + 2047, qrel in [0,64), ki in [0,2048)
    for (int i = tid; i < 2111; i += 256) bias_s[i] = bias2[q0 + i];
    // stage Q (64x64, source-swizzled)
    #pragma unroll
    for (int it = 0; it < 2; ++it) {
        int c = it * 256 + tid;
        int row = c >> 3, part = c & 7;
        int p = part ^ (row & 7);
        gll16(Qh + (bhT + q0 + row) * 64 + p * 8, PQ + c * 8);
    }
    __syncthreads();

    const int qrow = w * 16 + l15;
    bf16x8 qf[2];
    #pragma unroll
    for (int ks = 0; ks < 2; ++ks) {
        int pp = (ks * 4 + lh) ^ (qrow & 7);
        qf[ks] = *(const bf16x8*)(PQ + qrow * 64 + pp * 8);
    }

    // infini dot from registers (q-row = qrow), reduce over lh groups
    const float* mk = memkv + bh * 128;
    float di = 0.f;
    #pragma unroll
    for (int ks = 0; ks < 2; ++ks)
        #pragma unroll
        for (int e = 0; e < 8; ++e)
            di += (float)qf[ks][e] * mk[ks * 32 + lh * 8 + e];
    di += __shfl_xor(di, 16, 64);
    di += __shfl_xor(di, 32, 64);

    f32x4 o[4] = {};
    float lsum[4] = {};
    bf16* Psw = PQ + w * 16 * 88;

    for (int kt = 0; kt < SEQ / 64; ++kt) {
        __syncthreads();
        #pragma unroll
        for (int it = 0; it < 2; ++it) {
            int c = it * 256 + tid;
            int row = c >> 3, part = c & 7;
            int p = part ^ (row & 7);
            gll16(Kh + (bhT + kt * 64 + row) * 64 + p * 8, Ks + c * 8);
            gll16(Vt + ((size_t)bh * 64 + row) * SEQ + kt * 64 + p * 8, Vs + c * 8);
        }
        __syncthreads();

        // S = Q K^T
        f32x4 s_[4] = {};
        #pragma unroll
        for (int ks = 0; ks < 2; ++ks) {
            #pragma unroll
            for (int jk = 0; jk < 4; ++jk) {
                int row = jk * 16 + l15;
                int cc = (ks * 4 + lh) ^ (row & 7);
                bf16x8 kf = *(const bf16x8*)(Ks + row * 64 + cc * 8);
                s_[jk] = MFMA_BF16(qf[ks], kf, s_[jk]);
            }
        }

        // p = 2^(s*0.125*log2e + bias2) ; accumulate per-thread l partials
        #pragma unroll
        for (int jk = 0; jk < 4; ++jk) {
            int ki = jk * 16 + l15;
            #pragma unroll
            for (int r = 0; r < 4; ++r) {
                int qrel = w * 16 + lh * 4 + r;
                float pexp = exp2f(s_[jk][r] * (0.125f * LOG2E)
                                   + bias_s[qrel - (kt * 64 + ki) + 2047]);
                lsum[r] += pexp;
                Psw[(lh * 4 + r) * 88 + jk * 16 + l15] = (bf16)pexp;
            }
        }
        // wave-local P: ds_write -> ds_read ordering within wave, no barrier

        // O += P V
        #pragma unroll
        for (int ks = 0; ks < 2; ++ks) {
            bf16x8 pf = *(const bf16x8*)(Psw + l15 * 88 + ks * 32 + lh * 8);
            #pragma unroll
            for (int jd = 0; jd < 4; ++jd) {
                int row = jd * 16 + l15;
                int cc = (ks * 4 + lh) ^ (row & 7);
                bf16x8 vf = *(const bf16x8*)(Vs + row * 64 + cc * 8);
                o[jd] = MFMA_BF16(pf, vf, o[jd]);
            }
        }
    }

    // final l reduction across l15 (kv partition)
    #pragma unroll
    for (int d2 = 1; d2 < 16; d2 <<= 1) {
        #pragma unroll
        for (int r = 0; r < 4; ++r) lsum[r] += __shfl_xor(lsum[r], d2, 64);
    }

    float inv_l[4], sig[4];
    #pragma unroll
    for (int r = 0; r < 4; ++r) {
        inv_l[r] = 1.f / lsum[r];
        float dd = __shfl(di, lh * 4 + r, 64);
        sig[r] = 1.f / (1.f + __expf(-dd));
    }

    const int b = bh >> 4, h = bh & 15;
    #pragma unroll
    for (int jd = 0; jd < 4; ++jd) {
        int d = jd * 16 + l15;
        float mv = mk[64 + d];
        #pragma unroll
        for (int r = 0; r < 4; ++r) {
            int qi = q0 + w * 16 + lh * 4 + r;
            float val = o[jd][r] * inv_l[r] + 0.2f * sig[r] * mv;
            ao[((size_t)(b * SEQ + qi)) * D_MODEL + h * 64 + d] = (bf16)val;
        }
    }
}

// ---------------------------------------------------------------------------
extern "C" void kernel_launch(void* const* d_in, const int* in_sizes, int n_in,
                              void* d_out, int out_size, void* d_ws, size_t ws_size,
                              hipStream_t stream)
{
    const float* x        = (const float*)d_in[0];
    const float* Wq       = (const float*)d_in[1];
    const float* bq       = (const float*)d_in[2];
    const float* Wkv_down = (const float*)d_in[3];
    const float* bkv_down = (const float*)d_in[4];
    const float* Wkv_up   = (const float*)d_in[5];
    const float* bkv_up   = (const float*)d_in[6];
    const float* Wo       = (const float*)d_in[7];
    const float* bo       = (const float*)d_in[8];
    float* out = (float*)d_out;

    // workspace (no aliasing): ~56 MB
    char* p = (char*)d_ws;
    bf16* xb   = (bf16*)p;  p += 8388608;    // [4096][1024]
    bf16* Wqt  = (bf16*)p;  p += 2097152;    // [1024][1024]
    bf16* Wdt  = (bf16*)p;  p += 524288;     // [256][1024]
    bf16* Wut  = (bf16*)p;  p += 1048576;    // [2048][256]
    bf16* Wot  = (bf16*)p;  p += 2097152;    // [1024][1024]
    bf16* kvd  = (bf16*)p;  p += 2097152;    // [4096][256]
    bf16* Qh   = (bf16*)p;  p += 8388608;    // [32][2048][64]
    bf16* Kh   = (bf16*)p;  p += 8388608;    // [32][2048][64]
    bf16* Vh   = (bf16*)p;  p += 8388608;    // [32][2048][64]
    bf16* Vt   = (bf16*)p;  p += 8388608;    // [32][64][2048]
    bf16* ao   = (bf16*)p;  p += 8388608;    // [4096][1024]
    float* memb  = (float*)p; p += 16384;    // [32][128]
    float* bias2 = (float*)p; p += 16384;    // [4095]
    float2* rtab = (float2*)p; p += 524288;  // [2048][32]

    dim3 blk(256);

    // prep
    convert_bf16x8<<<dim3(M_ROWS * D_MODEL / 8 / 256), blk, 0, stream>>>(x, xb, M_ROWS * D_MODEL / 8);
    transpose_w<<<dim3(D_MODEL / 32, D_MODEL / 32), blk, 0, stream>>>(Wq, Wqt, D_MODEL, D_MODEL);
    transpose_w<<<dim3(D_LATENT / 32, D_MODEL / 32), blk, 0, stream>>>(Wkv_down, Wdt, D_MODEL, D_LATENT);
    transpose_w<<<dim3(2 * D_MODEL / 32, D_LATENT / 32), blk, 0, stream>>>(Wkv_up, Wut, D_LATENT, 2 * D_MODEL);
    transpose_w<<<dim3(D_MODEL / 32, D_MODEL / 32), blk, 0, stream>>>(Wo, Wot, D_MODEL, D_MODEL);
    rope_tab_kernel<<<dim3(SEQ * 32 / 256), blk, 0, stream>>>(rtab);
    bias_tab_kernel<<<dim3((2 * SEQ - 1 + 255) / 256), blk, 0, stream>>>(bias2);

    // projections (RoPE/pack fused)
    gemm_plain<1><<<dim3(D_LATENT / 128, M_ROWS / 128), blk, 0, stream>>>(
        xb, Wdt, bkv_down, kvd, D_LATENT, D_MODEL);
    gemm_q_rope<<<dim3(D_MODEL / 128, M_ROWS / 128), blk, 0, stream>>>(
        xb, Wqt, bq, rtab, Qh);
    gemm_kv_rope<<<dim3(2 * D_MODEL / 128, M_ROWS / 128), blk, 0, stream>>>(
        kvd, Wut, bkv_up, rtab, Kh, Vh);

    // V transpose + memory means
    transpose_v_b<<<dim3(BATCH * N_HEADS * (SEQ / 64)), blk, 0, stream>>>(Vh, Vt);
    mean_kv<<<dim3(BATCH * N_HEADS), blk, 0, stream>>>(Kh, Vh, memb);

    // attention (+infini fused)
    attn_mfma<<<dim3(SEQ / 64, BATCH * N_HEADS), blk, 0, stream>>>(
        Qh, Kh, Vt, bias2, memb, ao);

    // output projection
    gemm_plain<0><<<dim3(D_MODEL / 128, M_ROWS / 128), blk, 0, stream>>>(
        ao, Wot, bo, out, D_MODEL, D_MODEL);
}

// Round 6
// 255.952 us; speedup vs baseline: 11.6411x; 1.1055x over previous
//
#include <hip/hip_runtime.h>
#include <hip/hip_bf16.h>

#define D_MODEL 1024
#define N_HEADS 16
#define HEAD_DIM 64
#define D_LATENT 256
#define BATCH 2
#define SEQ 2048
#define M_ROWS (BATCH * SEQ)   // 4096

typedef __bf16 bf16;
typedef __attribute__((ext_vector_type(4))) __bf16 bf16x4;
typedef __attribute__((ext_vector_type(8))) __bf16 bf16x8;
typedef __attribute__((ext_vector_type(4))) float f32x4;

#define MFMA_BF16(a, b, c) __builtin_amdgcn_mfma_f32_16x16x32_bf16((a), (b), (c), 0, 0, 0)
#define LOG2E 1.4426950408889634f

__device__ __forceinline__ void gll16(const void* g, void* l) {
    __builtin_amdgcn_global_load_lds(
        (const __attribute__((address_space(1))) unsigned int*)g,
        (__attribute__((address_space(3))) unsigned int*)l, 16, 0, 0);
}

// ---------------------------------------------------------------------------
// prep_all: convert x -> bf16 | 4x weight transpose | rope table | bias table
// single launch, block-range dispatch
// ---------------------------------------------------------------------------
__device__ __forceinline__ void tw_body(
    const float* __restrict__ W, bf16* __restrict__ Wt, int K, int N,
    int b, float (*tw)[33], int tid)
{
    int nx = N / 32;
    int n0 = (b % nx) * 32, k0 = (b / nx) * 32;
    int c = tid & 31, r = tid >> 5;
    #pragma unroll
    for (int it = 0; it < 4; ++it)
        tw[r + it * 8][c] = W[(size_t)(k0 + r + it * 8) * N + n0 + c];
    __syncthreads();
    #pragma unroll
    for (int it = 0; it < 4; ++it)
        Wt[(size_t)(n0 + r + it * 8) * K + k0 + c] = (bf16)tw[c][r + it * 8];
}

__global__ __launch_bounds__(256) void prep_all(
    const float* __restrict__ x, bf16* __restrict__ xb,
    const float* __restrict__ Wq, bf16* __restrict__ Wqt,
    const float* __restrict__ Wd, bf16* __restrict__ Wdt,
    const float* __restrict__ Wu, bf16* __restrict__ Wut,
    const float* __restrict__ Wo, bf16* __restrict__ Wot,
    float2* __restrict__ rtab, float* __restrict__ bias2)
{
    __shared__ float tw[32][33];
    const int bid = blockIdx.x, tid = threadIdx.x;
    if (bid < 2048) {                       // x f32 -> bf16, 8/thread
        int i = bid * 256 + tid;            // exactly 524288 = 4096*1024/8
        const float4* s = ((const float4*)x) + (size_t)i * 2;
        float4 a = s[0], b = s[1];
        bf16x8 v;
        v[0] = (bf16)a.x; v[1] = (bf16)a.y; v[2] = (bf16)a.z; v[3] = (bf16)a.w;
        v[4] = (bf16)b.x; v[5] = (bf16)b.y; v[6] = (bf16)b.z; v[7] = (bf16)b.w;
        *(bf16x8*)(xb + (size_t)i * 8) = v;
    } else if (bid < 3072) {
        tw_body(Wq, Wqt, 1024, 1024, bid - 2048, tw, tid);
    } else if (bid < 3328) {
        tw_body(Wd, Wdt, 1024, 256, bid - 3072, tw, tid);
    } else if (bid < 3840) {
        tw_body(Wu, Wut, 256, 2048, bid - 3328, tw, tid);
    } else if (bid < 4864) {
        tw_body(Wo, Wot, 1024, 1024, bid - 3840, tw, tid);
    } else if (bid < 5120) {                // rope cos/sin table
        int i = (bid - 4864) * 256 + tid;   // < 65536
        int j = i & 31, t = i >> 5;
        float inv_freq = exp2f((float)j * -0.4152410118609203f);
        float ang = (float)t * inv_freq;
        float sn, cs; sincosf(ang, &sn, &cs);
        rtab[i] = make_float2(cs, sn);
    } else {                                // dist-bias table * log2e
        int i = (bid - 5120) * 256 + tid;
        if (i < 2 * SEQ - 1) {
            float d = (float)(i - (SEQ - 1));
            float ls  = -0.1f * logf(fabsf(d) + 1.0f);
            float dec = expf(-fmaxf(d, 0.0f) * 0.01f);
            bias2[i] = (ls + logf(dec + 1e-9f)) * LOG2E;
        }
    }
}

// ---------------------------------------------------------------------------
// Shared MFMA GEMM main loop body (128x128 tile, BK=32, 4 waves)
// ---------------------------------------------------------------------------
__device__ __forceinline__ void gemm_body(
    const bf16* __restrict__ A, const bf16* __restrict__ Bt, int K,
    bf16* As, bf16* Bs, f32x4 (&acc)[4][4],
    int m0, int n0, int tid, int l15, int lh, int wr, int wc)
{
    for (int k0 = 0; k0 < K; k0 += 32) {
        __syncthreads();
        #pragma unroll
        for (int it = 0; it < 2; ++it) {
            int c = it * 256 + tid;          // 0..511
            int row = c >> 2, part = c & 3;
            int p = part ^ ((row >> 1) & 3);
            gll16(A  + (size_t)(m0 + row) * K + k0 + p * 8, As + c * 8);
            gll16(Bt + (size_t)(n0 + row) * K + k0 + p * 8, Bs + c * 8);
        }
        __syncthreads();
        bf16x8 af[4], bg[4];
        #pragma unroll
        for (int i = 0; i < 4; ++i) {
            int row = wr * 64 + i * 16 + l15;
            int cc = lh ^ ((row >> 1) & 3);
            af[i] = *(const bf16x8*)(As + row * 32 + cc * 8);
        }
        #pragma unroll
        for (int j = 0; j < 4; ++j) {
            int row = wc * 64 + j * 16 + l15;
            int cc = lh ^ ((row >> 1) & 3);
            bg[j] = *(const bf16x8*)(Bs + row * 32 + cc * 8);
        }
        #pragma unroll
        for (int i = 0; i < 4; ++i)
            #pragma unroll
            for (int j = 0; j < 4; ++j)
                acc[i][j] = MFMA_BF16(af[i], bg[j], acc[i][j]);
    }
}

// ---------------------------------------------------------------------------
// Plain GEMM: C = A @ Bt^T + bias  (OUT_BF16: 1 -> bf16, 0 -> f32)
// ---------------------------------------------------------------------------
template<int OUT_BF16>
__global__ __launch_bounds__(256) void gemm_plain(
    const bf16* __restrict__ A, const bf16* __restrict__ Bt,
    const float* __restrict__ bias, void* __restrict__ C,
    int N, int K)
{
    __shared__ bf16 As[128 * 32];
    __shared__ bf16 Bs[128 * 32];
    const int tid = threadIdx.x, lane = tid & 63, w = tid >> 6;
    const int wr = w >> 1, wc = w & 1;
    const int l15 = lane & 15, lh = lane >> 4;
    const int m0 = blockIdx.y * 128, n0 = blockIdx.x * 128;
    f32x4 acc[4][4] = {};
    gemm_body(A, Bt, K, As, Bs, acc, m0, n0, tid, l15, lh, wr, wc);

    #pragma unroll
    for (int i = 0; i < 4; ++i) {
        int row = m0 + wr * 64 + i * 16 + lh * 4;
        #pragma unroll
        for (int j = 0; j < 4; ++j) {
            int col = n0 + wc * 64 + j * 16 + l15;
            float bv = bias[col];
            #pragma unroll
            for (int r = 0; r < 4; ++r) {
                float v = acc[i][j][r] + bv;
                if (OUT_BF16) ((bf16*)C)[(size_t)(row + r) * N + col] = (bf16)v;
                else          ((float*)C)[(size_t)(row + r) * N + col] = v;
            }
        }
    }
}

// ---------------------------------------------------------------------------
// Q-proj GEMM with fused RoPE + head-major pack.  N=1024, K=1024.
// ---------------------------------------------------------------------------
__global__ __launch_bounds__(256) void gemm_q_rope(
    const bf16* __restrict__ A, const bf16* __restrict__ Bt,
    const float* __restrict__ bias, const float2* __restrict__ rtab,
    bf16* __restrict__ Qh)
{
    __shared__ bf16 As[128 * 32];
    __shared__ bf16 Bs[128 * 32];
    const int tid = threadIdx.x, lane = tid & 63, w = tid >> 6;
    const int wr = w >> 1, wc = w & 1;
    const int l15 = lane & 15, lh = lane >> 4;
    const int m0 = blockIdx.y * 128, n0 = blockIdx.x * 128;
    f32x4 acc[4][4] = {};
    gemm_body(A, Bt, D_MODEL, As, Bs, acc, m0, n0, tid, l15, lh, wr, wc);

    const int head = blockIdx.x * 2 + wc;
    #pragma unroll
    for (int i = 0; i < 4; ++i) {
        #pragma unroll
        for (int r = 0; r < 4; ++r) {
            int m = m0 + wr * 64 + i * 16 + lh * 4 + r;
            int tpos = m & (SEQ - 1), b = m >> 11;
            bf16* orow = Qh + ((size_t)(b * N_HEADS + head) * SEQ + tpos) * 64;
            #pragma unroll
            for (int j01 = 0; j01 < 2; ++j01) {
                int jj = j01 * 16 + l15;
                float2 cssn = rtab[tpos * 32 + jj];
                float v1 = acc[i][j01][r]     + bias[head * 64 + jj];
                float v2 = acc[i][j01 + 2][r] + bias[head * 64 + jj + 32];
                orow[jj]      = (bf16)(v1 * cssn.x - v2 * cssn.y);
                orow[jj + 32] = (bf16)(v1 * cssn.y + v2 * cssn.x);
            }
        }
    }
}

// ---------------------------------------------------------------------------
// KV-up GEMM with fused RoPE(k) + pack.  N=2048, K=256.
// ---------------------------------------------------------------------------
__global__ __launch_bounds__(256) void gemm_kv_rope(
    const bf16* __restrict__ A, const bf16* __restrict__ Bt,
    const float* __restrict__ bias, const float2* __restrict__ rtab,
    bf16* __restrict__ Kh, bf16* __restrict__ Vh)
{
    __shared__ bf16 As[128 * 32];
    __shared__ bf16 Bs[128 * 32];
    const int tid = threadIdx.x, lane = tid & 63, w = tid >> 6;
    const int wr = w >> 1, wc = w & 1;
    const int l15 = lane & 15, lh = lane >> 4;
    const int m0 = blockIdx.y * 128, n0 = blockIdx.x * 128;
    f32x4 acc[4][4] = {};
    gemm_body(A, Bt, D_LATENT, As, Bs, acc, m0, n0, tid, l15, lh, wr, wc);

    const int head = blockIdx.x;
    if (wc == 0) {
        #pragma unroll
        for (int i = 0; i < 4; ++i) {
            #pragma unroll
            for (int r = 0; r < 4; ++r) {
                int m = m0 + wr * 64 + i * 16 + lh * 4 + r;
                int tpos = m & (SEQ - 1), b = m >> 11;
                bf16* orow = Kh + ((size_t)(b * N_HEADS + head) * SEQ + tpos) * 64;
                #pragma unroll
                for (int j01 = 0; j01 < 2; ++j01) {
                    int jj = j01 * 16 + l15;
                    float2 cssn = rtab[tpos * 32 + jj];
                    float v1 = acc[i][j01][r]     + bias[head * 128 + jj];
                    float v2 = acc[i][j01 + 2][r] + bias[head * 128 + jj + 32];
                    orow[jj]      = (bf16)(v1 * cssn.x - v2 * cssn.y);
                    orow[jj + 32] = (bf16)(v1 * cssn.y + v2 * cssn.x);
                }
            }
        }
    } else {
        #pragma unroll
        for (int i = 0; i < 4; ++i) {
            #pragma unroll
            for (int r = 0; r < 4; ++r) {
                int m = m0 + wr * 64 + i * 16 + lh * 4 + r;
                int tpos = m & (SEQ - 1), b = m >> 11;
                bf16* orow = Vh + ((size_t)(b * N_HEADS + head) * SEQ + tpos) * 64;
                #pragma unroll
                for (int j = 0; j < 4; ++j) {
                    int d = j * 16 + l15;
                    orow[d] = (bf16)(acc[i][j][r] + bias[head * 128 + 64 + d]);
                }
            }
        }
    }
}

// ---------------------------------------------------------------------------
// Vh [BH][T][64] -> Vt [BH][64][T]
// ---------------------------------------------------------------------------
__global__ __launch_bounds__(256) void transpose_v_b(
    const bf16* __restrict__ Vh, bf16* __restrict__ Vt)
{
    __shared__ bf16 tile[64][72];
    int blk = blockIdx.x;          // bh*32 + tt
    int tt = blk & 31, bh = blk >> 5;
    int t0 = tt * 64;
    int tid = threadIdx.x;
    #pragma unroll
    for (int it = 0; it < 2; ++it) {
        int lin = it * 256 + tid;
        int r = lin >> 3, c8 = (lin & 7) * 8;
        bf16x8 v = *(const bf16x8*)(Vh + ((size_t)bh * SEQ + t0 + r) * 64 + c8);
        #pragma unroll
        for (int e = 0; e < 8; ++e) tile[c8 + e][r] = v[e];
    }
    __syncthreads();
    #pragma unroll
    for (int it = 0; it < 2; ++it) {
        int lin = it * 256 + tid;
        int d = lin >> 3, seg = (lin & 7) * 8;
        bf16x8 v = *(const bf16x8*)(&tile[d][seg]);
        *(bf16x8*)(Vt + ((size_t)bh * 64 + d) * SEQ + t0 + seg) = v;
    }
}

// ---------------------------------------------------------------------------
// memory means, phase 1: part[seg][bh][128] partial sums (vectorized)
// grid = 32 bh x 8 seg, 256 threads = 16 row-groups x 16 d-quads
// ---------------------------------------------------------------------------
__global__ __launch_bounds__(256) void mean_part(
    const bf16* __restrict__ Kh, const bf16* __restrict__ Vh,
    float* __restrict__ part)
{
    __shared__ float red[4][128];
    const int bh = blockIdx.x >> 3, seg = blockIdx.x & 7;
    const int tid = threadIdx.x;
    const int rr = tid >> 4, l16 = tid & 15;
    float ak[4] = {}, av[4] = {};
    #pragma unroll 4
    for (int i = 0; i < 16; ++i) {
        int row = seg * 256 + i * 16 + rr;
        const bf16* kp = Kh + ((size_t)bh * SEQ + row) * 64 + l16 * 4;
        const bf16* vp = Vh + ((size_t)bh * SEQ + row) * 64 + l16 * 4;
        bf16x4 k4 = *(const bf16x4*)kp;
        bf16x4 v4 = *(const bf16x4*)vp;
        #pragma unroll
        for (int e = 0; e < 4; ++e) { ak[e] += (float)k4[e]; av[e] += (float)v4[e]; }
    }
    #pragma unroll
    for (int m = 16; m <= 32; m <<= 1)
        #pragma unroll
        for (int e = 0; e < 4; ++e) {
            ak[e] += __shfl_xor(ak[e], m, 64);
            av[e] += __shfl_xor(av[e], m, 64);
        }
    int wv = tid >> 6;
    if ((tid & 63) < 16) {
        #pragma unroll
        for (int e = 0; e < 4; ++e) {
            red[wv][l16 * 4 + e]      = ak[e];
            red[wv][64 + l16 * 4 + e] = av[e];
        }
    }
    __syncthreads();
    if (tid < 128) {
        float s = red[0][tid] + red[1][tid] + red[2][tid] + red[3][tid];
        part[((size_t)seg * 32 + bh) * 128 + tid] = s;
    }
}

// phase 2: memkv[bh][128] = sum over seg / SEQ      grid = 16 x 256
__global__ void mean_final(const float* __restrict__ part, float* __restrict__ memkv)
{
    int idx = blockIdx.x * 256 + threadIdx.x;   // < 4096
    float s = 0.f;
    #pragma unroll
    for (int g = 0; g < 8; ++g) s += part[(size_t)g * 4096 + idx];
    memkv[idx] = s * (1.f / SEQ);
}

// ---------------------------------------------------------------------------
// MFMA flash attention, swapped-QK (S^T), no-max softmax, fused infini.
// grid = (SEQ/64, B*H), 256 threads (4 waves x 16 q-rows), KVBLK=64.
// ---------------------------------------------------------------------------
__global__ __launch_bounds__(256) void attn_mfma(
    const bf16* __restrict__ Qh,     // [BH][T][64]
    const bf16* __restrict__ Kh,     // [BH][T][64]
    const bf16* __restrict__ Vt,     // [BH][64][T]
    const float* __restrict__ bias2, // [4095], pre-scaled by log2e
    const float* __restrict__ memkv, // [BH][128]
    bf16* __restrict__ ao)           // [B][T][H][64]
{
    __shared__ bf16 PQ[4 * 16 * 88];   // Q tile (8 KB) then per-wave P
    __shared__ bf16 Ks[64 * 64];       // 8 KB, swizzled
    __shared__ bf16 Vs[64 * 64];       // 8 KB, swizzled [d][kv]
    __shared__ float bias_s[2112];     // 8.4 KB window

    const int tid = threadIdx.x;
    const int lane = tid & 63;
    const int w = tid >> 6;
    const int l15 = lane & 15, lh = lane >> 4;
    const int bh = blockIdx.y;
    const int q0 = blockIdx.x * 64;
    const size_t bhT = (size_t)bh * SEQ;

    for (int i = tid; i < 2111; i += 256) bias_s[i] = bias2[q0 + i];
    #pragma unroll
    for (int it = 0; it < 2; ++it) {
        int c = it * 256 + tid;
        int row = c >> 3, part = c & 7;
        int p = part ^ (row & 7);
        gll16(Qh + (bhT + q0 + row) * 64 + p * 8, PQ + c * 8);
    }
    __syncthreads();

    const int qrow = w * 16 + l15;     // wave's q-row (lane-owned after swap)
    bf16x8 qf[2];
    #pragma unroll
    for (int ks = 0; ks < 2; ++ks) {
        int pp = (ks * 4 + lh) ^ (qrow & 7);
        qf[ks] = *(const bf16x8*)(PQ + qrow * 64 + pp * 8);
    }

    // infini dot (q-row = qrow), reduce over lh groups
    const float* mk = memkv + bh * 128;
    float di = 0.f;
    #pragma unroll
    for (int ks = 0; ks < 2; ++ks)
        #pragma unroll
        for (int e = 0; e < 8; ++e)
            di += (float)qf[ks][e] * mk[ks * 32 + lh * 8 + e];
    di += __shfl_xor(di, 16, 64);
    di += __shfl_xor(di, 32, 64);

    f32x4 o[4] = {};
    float lsum = 0.f;
    bf16* Psw = PQ + w * 16 * 88;

    for (int kt = 0; kt < SEQ / 64; ++kt) {
        __syncthreads();
        #pragma unroll
        for (int it = 0; it < 2; ++it) {
            int c = it * 256 + tid;
            int row = c >> 3, part = c & 7;
            int p = part ^ (row & 7);
            gll16(Kh + (bhT + kt * 64 + row) * 64 + p * 8, Ks + c * 8);
            gll16(Vt + ((size_t)bh * 64 + row) * SEQ + kt * 64 + p * 8, Vs + c * 8);
        }
        __syncthreads();

        // S^T = K Q^T : lane owns q-col = l15, kv rows = jk*16 + lh*4 + r
        f32x4 s_[4] = {};
        #pragma unroll
        for (int ks = 0; ks < 2; ++ks) {
            #pragma unroll
            for (int jk = 0; jk < 4; ++jk) {
                int row = jk * 16 + l15;
                int cc = (ks * 4 + lh) ^ (row & 7);
                bf16x8 kf = *(const bf16x8*)(Ks + row * 64 + cc * 8);
                s_[jk] = MFMA_BF16(kf, qf[ks], s_[jk]);
            }
        }

        // p = 2^(s*c + bias); packed b64 P writes (lane-local q-row)
        #pragma unroll
        for (int jk = 0; jk < 4; ++jk) {
            int idx0 = (w * 16 + l15) - (kt * 64 + jk * 16 + lh * 4) + 2047;
            bf16x4 pb;
            #pragma unroll
            for (int r = 0; r < 4; ++r) {
                float pexp = exp2f(s_[jk][r] * (0.125f * LOG2E) + bias_s[idx0 - r]);
                lsum += pexp;
                pb[r] = (bf16)pexp;
            }
            *(bf16x4*)(Psw + l15 * 88 + jk * 16 + lh * 4) = pb;
        }
        // wave-local P: ds_write -> ds_read ordering within wave, no barrier

        // O += P V
        #pragma unroll
        for (int ks = 0; ks < 2; ++ks) {
            bf16x8 pf = *(const bf16x8*)(Psw + l15 * 88 + ks * 32 + lh * 8);
            #pragma unroll
            for (int jd = 0; jd < 4; ++jd) {
                int row = jd * 16 + l15;
                int cc = (ks * 4 + lh) ^ (row & 7);
                bf16x8 vf = *(const bf16x8*)(Vs + row * 64 + cc * 8);
                o[jd] = MFMA_BF16(pf, vf, o[jd]);
            }
        }
    }

    // l lives per-lane for q-row = qrow: reduce over lh groups
    lsum += __shfl_xor(lsum, 16, 64);
    lsum += __shfl_xor(lsum, 32, 64);

    float inv_l[4], sig[4];
    #pragma unroll
    for (int r = 0; r < 4; ++r) {
        int src = lh * 4 + r;                       // q-row owner lane
        inv_l[r] = 1.f / __shfl(lsum, src, 64);
        float dd = __shfl(di, src, 64);
        sig[r] = 1.f / (1.f + __expf(-dd));
    }

    const int b = bh >> 4, h = bh & 15;
    #pragma unroll
    for (int jd = 0; jd < 4; ++jd) {
        int d = jd * 16 + l15;
        float mv = mk[64 + d];
        #pragma unroll
        for (int r = 0; r < 4; ++r) {
            int qi = q0 + w * 16 + lh * 4 + r;
            float val = o[jd][r] * inv_l[r] + 0.2f * sig[r] * mv;
            ao[((size_t)(b * SEQ + qi)) * D_MODEL + h * 64 + d] = (bf16)val;
        }
    }
}

// ---------------------------------------------------------------------------
extern "C" void kernel_launch(void* const* d_in, const int* in_sizes, int n_in,
                              void* d_out, int out_size, void* d_ws, size_t ws_size,
                              hipStream_t stream)
{
    const float* x        = (const float*)d_in[0];
    const float* Wq       = (const float*)d_in[1];
    const float* bq       = (const float*)d_in[2];
    const float* Wkv_down = (const float*)d_in[3];
    const float* bkv_down = (const float*)d_in[4];
    const float* Wkv_up   = (const float*)d_in[5];
    const float* bkv_up   = (const float*)d_in[6];
    const float* Wo       = (const float*)d_in[7];
    const float* bo       = (const float*)d_in[8];
    float* out = (float*)d_out;

    char* p = (char*)d_ws;
    bf16* xb   = (bf16*)p;  p += 8388608;    // [4096][1024]
    bf16* Wqt  = (bf16*)p;  p += 2097152;
    bf16* Wdt  = (bf16*)p;  p += 524288;
    bf16* Wut  = (bf16*)p;  p += 1048576;
    bf16* Wot  = (bf16*)p;  p += 2097152;
    bf16* kvd  = (bf16*)p;  p += 2097152;    // [4096][256]
    bf16* Qh   = (bf16*)p;  p += 8388608;    // [32][2048][64]
    bf16* Kh   = (bf16*)p;  p += 8388608;
    bf16* Vh   = (bf16*)p;  p += 8388608;
    bf16* Vt   = (bf16*)p;  p += 8388608;    // [32][64][2048]
    bf16* ao   = (bf16*)p;  p += 8388608;    // [4096][1024]
    float* memb  = (float*)p; p += 16384;    // [32][128]
    float* bias2 = (float*)p; p += 16384;    // [4095]
    float2* rtab = (float2*)p; p += 524288;  // [2048][32]
    float* partb = (float*)p; p += 131072;   // [8][32][128]

    dim3 blk(256);

    // fused prep: convert + 4 transposes + rope table + bias table
    prep_all<<<dim3(5136), blk, 0, stream>>>(
        x, xb, Wq, Wqt, Wkv_down, Wdt, Wkv_up, Wut, Wo, Wot, rtab, bias2);

    // projections (RoPE/pack fused)
    gemm_plain<1><<<dim3(D_LATENT / 128, M_ROWS / 128), blk, 0, stream>>>(
        xb, Wdt, bkv_down, kvd, D_LATENT, D_MODEL);
    gemm_q_rope<<<dim3(D_MODEL / 128, M_ROWS / 128), blk, 0, stream>>>(
        xb, Wqt, bq, rtab, Qh);
    gemm_kv_rope<<<dim3(2 * D_MODEL / 128, M_ROWS / 128), blk, 0, stream>>>(
        kvd, Wut, bkv_up, rtab, Kh, Vh);

    // V transpose + memory means (2-phase vectorized)
    transpose_v_b<<<dim3(BATCH * N_HEADS * (SEQ / 64)), blk, 0, stream>>>(Vh, Vt);
    mean_part<<<dim3(BATCH * N_HEADS * 8), blk, 0, stream>>>(Kh, Vh, partb);
    mean_final<<<dim3(16), blk, 0, stream>>>(partb, memb);

    // attention (+infini fused)
    attn_mfma<<<dim3(SEQ / 64, BATCH * N_HEADS), blk, 0, stream>>>(
        Qh, Kh, Vt, bias2, memb, ao);

    // output projection
    gemm_plain<0><<<dim3(D_MODEL / 128, M_ROWS / 128), blk, 0, stream>>>(
        ao, Wot, bo, out, D_MODEL, D_MODEL);
}

// Round 7
// 223.041 us; speedup vs baseline: 13.3589x; 1.1476x over previous
//
#include <hip/hip_runtime.h>
#include <hip/hip_bf16.h>

#define D_MODEL 1024
#define N_HEADS 16
#define HEAD_DIM 64
#define D_LATENT 256
#define BATCH 2
#define SEQ 2048
#define M_ROWS (BATCH * SEQ)   // 4096

typedef __bf16 bf16;
typedef __attribute__((ext_vector_type(4))) __bf16 bf16x4;
typedef __attribute__((ext_vector_type(8))) __bf16 bf16x8;
typedef __attribute__((ext_vector_type(4))) float f32x4;

#define MFMA_BF16(a, b, c) __builtin_amdgcn_mfma_f32_16x16x32_bf16((a), (b), (c), 0, 0, 0)
#define LOG2E 1.4426950408889634f
#define SBAR() __builtin_amdgcn_s_barrier()
#define SCHED0() __builtin_amdgcn_sched_barrier(0)

__device__ __forceinline__ void gll16(const void* g, void* l) {
    __builtin_amdgcn_global_load_lds(
        (const __attribute__((address_space(1))) unsigned int*)g,
        (__attribute__((address_space(3))) unsigned int*)l, 16, 0, 0);
}
__device__ __forceinline__ void vwait4() { asm volatile("s_waitcnt vmcnt(4)" ::: "memory"); }
__device__ __forceinline__ void vwait0() { asm volatile("s_waitcnt vmcnt(0)" ::: "memory"); }

// ---------------------------------------------------------------------------
// prep_all: convert x | 4x weight transpose | rope table | bias table | memb=0
// ---------------------------------------------------------------------------
__device__ __forceinline__ void tw_body(
    const float* __restrict__ W, bf16* __restrict__ Wt, int K, int N,
    int b, float (*tw)[33], int tid)
{
    int nx = N / 32;
    int n0 = (b % nx) * 32, k0 = (b / nx) * 32;
    int c = tid & 31, r = tid >> 5;
    #pragma unroll
    for (int it = 0; it < 4; ++it)
        tw[r + it * 8][c] = W[(size_t)(k0 + r + it * 8) * N + n0 + c];
    __syncthreads();
    #pragma unroll
    for (int it = 0; it < 4; ++it)
        Wt[(size_t)(n0 + r + it * 8) * K + k0 + c] = (bf16)tw[c][r + it * 8];
}

__global__ __launch_bounds__(256) void prep_all(
    const float* __restrict__ x, bf16* __restrict__ xb,
    const float* __restrict__ Wq, bf16* __restrict__ Wqt,
    const float* __restrict__ Wd, bf16* __restrict__ Wdt,
    const float* __restrict__ Wu, bf16* __restrict__ Wut,
    const float* __restrict__ Wo, bf16* __restrict__ Wot,
    float2* __restrict__ rtab, float* __restrict__ bias2,
    float* __restrict__ memb)
{
    __shared__ float tw[32][33];
    const int bid = blockIdx.x, tid = threadIdx.x;
    if (bid < 2048) {
        int i = bid * 256 + tid;
        const float4* s = ((const float4*)x) + (size_t)i * 2;
        float4 a = s[0], b = s[1];
        bf16x8 v;
        v[0] = (bf16)a.x; v[1] = (bf16)a.y; v[2] = (bf16)a.z; v[3] = (bf16)a.w;
        v[4] = (bf16)b.x; v[5] = (bf16)b.y; v[6] = (bf16)b.z; v[7] = (bf16)b.w;
        *(bf16x8*)(xb + (size_t)i * 8) = v;
    } else if (bid < 3072) {
        tw_body(Wq, Wqt, 1024, 1024, bid - 2048, tw, tid);
    } else if (bid < 3328) {
        tw_body(Wd, Wdt, 1024, 256, bid - 3072, tw, tid);
    } else if (bid < 3840) {
        tw_body(Wu, Wut, 256, 2048, bid - 3328, tw, tid);
    } else if (bid < 4864) {
        tw_body(Wo, Wot, 1024, 1024, bid - 3840, tw, tid);
    } else if (bid < 5120) {
        int i = (bid - 4864) * 256 + tid;
        int j = i & 31, t = i >> 5;
        float inv_freq = exp2f((float)j * -0.4152410118609203f);
        float ang = (float)t * inv_freq;
        float sn, cs; sincosf(ang, &sn, &cs);
        rtab[i] = make_float2(cs, sn);
    } else {
        int i = (bid - 5120) * 256 + tid;    // < 4096
        if (i < 2 * SEQ - 1) {
            float d = (float)(i - (SEQ - 1));
            float ls  = -0.1f * logf(fabsf(d) + 1.0f);
            float dec = expf(-fmaxf(d, 0.0f) * 0.01f);
            bias2[i] = (ls + logf(dec + 1e-9f)) * LOG2E;
        }
        if (i < 4096) memb[i] = 0.f;
    }
}

// ---------------------------------------------------------------------------
// Double-buffered MFMA GEMM body (128x128 tile, BK=32, 4 waves).
// sh layout (bf16): As0[4096] As1[4096] Bs0[4096] Bs1[4096] = 32 KB
// Counted vmcnt(4) pipeline, raw barriers (no compiler vmcnt(0) drain).
// ---------------------------------------------------------------------------
__device__ __forceinline__ void stage_gemm(
    const bf16* __restrict__ A, const bf16* __restrict__ Bt, int K, int k0,
    bf16* As, bf16* Bs, int m0, int n0, int tid)
{
    #pragma unroll
    for (int it = 0; it < 2; ++it) {
        int c = it * 256 + tid;          // 0..511
        int row = c >> 2, part = c & 3;
        int p = part ^ ((row >> 1) & 3);
        gll16(A  + (size_t)(m0 + row) * K + k0 + p * 8, As + c * 8);
        gll16(Bt + (size_t)(n0 + row) * K + k0 + p * 8, Bs + c * 8);
    }
}

__device__ __forceinline__ void gemm_body(
    const bf16* __restrict__ A, const bf16* __restrict__ Bt, int K,
    bf16* sh, f32x4 (&acc)[4][4],
    int m0, int n0, int tid, int l15, int lh, int wr, int wc)
{
    stage_gemm(A, Bt, K, 0, sh, sh + 8192, m0, n0, tid);
    int cur = 0;
    for (int k0 = 0; k0 < K; k0 += 32) {
        if (k0 + 32 < K) {
            stage_gemm(A, Bt, K, k0 + 32, sh + (cur ^ 1) * 4096,
                       sh + 8192 + (cur ^ 1) * 4096, m0, n0, tid);
            vwait4();
        } else {
            vwait0();
        }
        SCHED0(); SBAR(); SCHED0();
        const bf16* As = sh + cur * 4096;
        const bf16* Bs = sh + 8192 + cur * 4096;
        bf16x8 af[4], bg[4];
        #pragma unroll
        for (int i = 0; i < 4; ++i) {
            int row = wr * 64 + i * 16 + l15;
            int cc = lh ^ ((row >> 1) & 3);
            af[i] = *(const bf16x8*)(As + row * 32 + cc * 8);
        }
        #pragma unroll
        for (int j = 0; j < 4; ++j) {
            int row = wc * 64 + j * 16 + l15;
            int cc = lh ^ ((row >> 1) & 3);
            bg[j] = *(const bf16x8*)(Bs + row * 32 + cc * 8);
        }
        #pragma unroll
        for (int i = 0; i < 4; ++i)
            #pragma unroll
            for (int j = 0; j < 4; ++j)
                acc[i][j] = MFMA_BF16(af[i], bg[j], acc[i][j]);
        SCHED0(); SBAR(); SCHED0();
        cur ^= 1;
    }
}

// ---------------------------------------------------------------------------
// Merged Q-proj (+RoPE pack) and KV-down GEMM.  grid = (10, 32).
// bx<8: q_rope cols (N=1024); bx>=8: kv-down cols (N=256).
// ---------------------------------------------------------------------------
__global__ __launch_bounds__(256) void gemm_qkvd(
    const bf16* __restrict__ xb,
    const bf16* __restrict__ Wqt, const float* __restrict__ bq,
    const float2* __restrict__ rtab, bf16* __restrict__ Qh,
    const bf16* __restrict__ Wdt, const float* __restrict__ bkvd,
    bf16* __restrict__ kvd)
{
    __shared__ bf16 sh[16384];
    const int tid = threadIdx.x, lane = tid & 63, w = tid >> 6;
    const int wr = w >> 1, wc = w & 1;
    const int l15 = lane & 15, lh = lane >> 4;
    const int bx = blockIdx.x;
    const int m0 = blockIdx.y * 128;
    const bf16* Bt = (bx < 8) ? Wqt : Wdt;
    const int n0 = (bx < 8) ? bx * 128 : (bx - 8) * 128;

    f32x4 acc[4][4] = {};
    gemm_body(xb, Bt, D_MODEL, sh, acc, m0, n0, tid, l15, lh, wr, wc);

    if (bx < 8) {
        const int head = bx * 2 + wc;
        #pragma unroll
        for (int i = 0; i < 4; ++i) {
            #pragma unroll
            for (int r = 0; r < 4; ++r) {
                int m = m0 + wr * 64 + i * 16 + lh * 4 + r;
                int tpos = m & (SEQ - 1), b = m >> 11;
                bf16* orow = Qh + ((size_t)(b * N_HEADS + head) * SEQ + tpos) * 64;
                #pragma unroll
                for (int j01 = 0; j01 < 2; ++j01) {
                    int jj = j01 * 16 + l15;
                    float2 cssn = rtab[tpos * 32 + jj];
                    float v1 = acc[i][j01][r]     + bq[head * 64 + jj];
                    float v2 = acc[i][j01 + 2][r] + bq[head * 64 + jj + 32];
                    orow[jj]      = (bf16)(v1 * cssn.x - v2 * cssn.y);
                    orow[jj + 32] = (bf16)(v1 * cssn.y + v2 * cssn.x);
                }
            }
        }
    } else {
        #pragma unroll
        for (int i = 0; i < 4; ++i) {
            int row = m0 + wr * 64 + i * 16 + lh * 4;
            #pragma unroll
            for (int j = 0; j < 4; ++j) {
                int col = n0 + wc * 64 + j * 16 + l15;
                float bv = bkvd[col];
                #pragma unroll
                for (int r = 0; r < 4; ++r)
                    kvd[(size_t)(row + r) * D_LATENT + col] = (bf16)(acc[i][j][r] + bv);
            }
        }
    }
}

// ---------------------------------------------------------------------------
// KV-up GEMM: fused RoPE(k)->Kh, LDS-transpose V->Vt, mean atomics->memb.
// grid = (16, 32): bx = head, one 128-col tile = 64 k-dims + 64 v-dims.
// ---------------------------------------------------------------------------
__global__ __launch_bounds__(256) void gemm_kv_rope(
    const bf16* __restrict__ A, const bf16* __restrict__ Bt,
    const float* __restrict__ bias, const float2* __restrict__ rtab,
    bf16* __restrict__ Kh, bf16* __restrict__ Vt, float* __restrict__ memb)
{
    __shared__ bf16 sh[16384];
    const int tid = threadIdx.x, lane = tid & 63, w = tid >> 6;
    const int wr = w >> 1, wc = w & 1;
    const int l15 = lane & 15, lh = lane >> 4;
    const int head = blockIdx.x;
    const int m0 = blockIdx.y * 128;
    const int b = m0 >> 11;
    const int bh = b * N_HEADS + head;
    const int tpos0 = m0 & (SEQ - 1);

    f32x4 acc[4][4] = {};
    gemm_body(A, Bt, D_LATENT, sh, acc, m0, head * 128, tid, l15, lh, wr, wc);
    // trailing SBAR in body: all waves done with sh -> reusable

    if (wc == 0) {
        // K half: rope + write Kh + column partial sums
        float s0 = 0.f, s1 = 0.f, s2 = 0.f, s3 = 0.f;
        #pragma unroll
        for (int i = 0; i < 4; ++i) {
            #pragma unroll
            for (int r = 0; r < 4; ++r) {
                int m = m0 + wr * 64 + i * 16 + lh * 4 + r;
                int tpos = m & (SEQ - 1);
                bf16* orow = Kh + ((size_t)bh * SEQ + tpos) * 64;
                // cols l15 / l15+32
                float2 ca = rtab[tpos * 32 + l15];
                float v1 = acc[i][0][r] + bias[head * 128 + l15];
                float v2 = acc[i][2][r] + bias[head * 128 + l15 + 32];
                float o1 = v1 * ca.x - v2 * ca.y;
                float o2 = v1 * ca.y + v2 * ca.x;
                orow[l15]      = (bf16)o1;
                orow[l15 + 32] = (bf16)o2;
                // cols 16+l15 / 48+l15
                float2 cb = rtab[tpos * 32 + 16 + l15];
                float v3 = acc[i][1][r] + bias[head * 128 + 16 + l15];
                float v4 = acc[i][3][r] + bias[head * 128 + 48 + l15];
                float o3 = v3 * cb.x - v4 * cb.y;
                float o4 = v3 * cb.y + v4 * cb.x;
                orow[16 + l15] = (bf16)o3;
                orow[48 + l15] = (bf16)o4;
                s0 += o1; s1 += o3; s2 += o2; s3 += o4;
            }
        }
        s0 += __shfl_xor(s0, 16, 64); s0 += __shfl_xor(s0, 32, 64);
        s1 += __shfl_xor(s1, 16, 64); s1 += __shfl_xor(s1, 32, 64);
        s2 += __shfl_xor(s2, 16, 64); s2 += __shfl_xor(s2, 32, 64);
        s3 += __shfl_xor(s3, 16, 64); s3 += __shfl_xor(s3, 32, 64);
        if (lane < 16) {
            const float sc = 1.f / SEQ;
            atomicAdd(&memb[bh * 128 + l15],      s0 * sc);
            atomicAdd(&memb[bh * 128 + 16 + l15], s1 * sc);
            atomicAdd(&memb[bh * 128 + 32 + l15], s2 * sc);
            atomicAdd(&memb[bh * 128 + 48 + l15], s3 * sc);
        }
    } else {
        // V half: acc -> sh[d][t] (pitch 136) + column sums
        float sv[4] = {};
        #pragma unroll
        for (int i = 0; i < 4; ++i) {
            #pragma unroll
            for (int j = 0; j < 4; ++j) {
                int d = j * 16 + l15;
                float bv = bias[head * 128 + 64 + d];
                #pragma unroll
                for (int r = 0; r < 4; ++r) {
                    int t = wr * 64 + i * 16 + lh * 4 + r;
                    float v = acc[i][j][r] + bv;
                    sh[d * 136 + t] = (bf16)v;
                    sv[j] += v;
                }
            }
        }
        #pragma unroll
        for (int j = 0; j < 4; ++j) {
            sv[j] += __shfl_xor(sv[j], 16, 64);
            sv[j] += __shfl_xor(sv[j], 32, 64);
        }
        if (lane < 16) {
            const float sc = 1.f / SEQ;
            #pragma unroll
            for (int j = 0; j < 4; ++j)
                atomicAdd(&memb[bh * 128 + 64 + j * 16 + l15], sv[j] * sc);
        }
    }
    __syncthreads();
    // cooperative coalesced Vt write: thread -> (d, 32-t segment)
    {
        int d = tid >> 2, seg = tid & 3;
        bf16* dst = Vt + ((size_t)bh * 64 + d) * SEQ + tpos0 + seg * 32;
        #pragma unroll
        for (int e = 0; e < 4; ++e)
            *(bf16x8*)(dst + e * 8) = *(const bf16x8*)(sh + d * 136 + seg * 32 + e * 8);
    }
}

// ---------------------------------------------------------------------------
// Plain GEMM (o-proj): C = A @ Bt^T + bias -> f32
// ---------------------------------------------------------------------------
__global__ __launch_bounds__(256) void gemm_out(
    const bf16* __restrict__ A, const bf16* __restrict__ Bt,
    const float* __restrict__ bias, float* __restrict__ C)
{
    __shared__ bf16 sh[16384];
    const int tid = threadIdx.x, lane = tid & 63, w = tid >> 6;
    const int wr = w >> 1, wc = w & 1;
    const int l15 = lane & 15, lh = lane >> 4;
    const int m0 = blockIdx.y * 128, n0 = blockIdx.x * 128;
    f32x4 acc[4][4] = {};
    gemm_body(A, Bt, D_MODEL, sh, acc, m0, n0, tid, l15, lh, wr, wc);

    #pragma unroll
    for (int i = 0; i < 4; ++i) {
        int row = m0 + wr * 64 + i * 16 + lh * 4;
        #pragma unroll
        for (int j = 0; j < 4; ++j) {
            int col = n0 + wc * 64 + j * 16 + l15;
            float bv = bias[col];
            #pragma unroll
            for (int r = 0; r < 4; ++r)
                C[(size_t)(row + r) * D_MODEL + col] = acc[i][j][r] + bv;
        }
    }
}

// ---------------------------------------------------------------------------
// MFMA flash attention: swapped-QK, no-max softmax, fused infini,
// double-buffered K/V staging with counted vmcnt.
// grid = (SEQ/64, B*H), 256 threads (4 waves x 16 q-rows), KVBLK=64.
// LDS: PQ 11264 + Ks 16K + Vs 16K + bias 8448 = ~52.5 KB -> 3 blocks/CU.
// ---------------------------------------------------------------------------
__global__ __launch_bounds__(256) void attn_mfma(
    const bf16* __restrict__ Qh,     // [BH][T][64]
    const bf16* __restrict__ Kh,     // [BH][T][64]
    const bf16* __restrict__ Vt,     // [BH][64][T]
    const float* __restrict__ bias2, // [4095], * log2e
    const float* __restrict__ memkv, // [BH][128]
    bf16* __restrict__ ao)           // [B][T][H][64]
{
    __shared__ bf16 PQ[4 * 16 * 88];
    __shared__ bf16 Ks[2 * 64 * 64];
    __shared__ bf16 Vs[2 * 64 * 64];
    __shared__ float bias_s[2112];

    const int tid = threadIdx.x;
    const int lane = tid & 63;
    const int w = tid >> 6;
    const int l15 = lane & 15, lh = lane >> 4;
    const int bh = blockIdx.y;
    const int q0 = blockIdx.x * 64;
    const size_t bhT = (size_t)bh * SEQ;

    for (int i = tid; i < 2111; i += 256) bias_s[i] = bias2[q0 + i];
    #pragma unroll
    for (int it = 0; it < 2; ++it) {
        int c = it * 256 + tid;
        int row = c >> 3, part = c & 7;
        int p = part ^ (row & 7);
        gll16(Qh + (bhT + q0 + row) * 64 + p * 8, PQ + c * 8);
    }
    // stage tile 0
    #pragma unroll
    for (int it = 0; it < 2; ++it) {
        int c = it * 256 + tid;
        int row = c >> 3, part = c & 7;
        int p = part ^ (row & 7);
        gll16(Kh + (bhT + row) * 64 + p * 8, Ks + c * 8);
        gll16(Vt + ((size_t)bh * 64 + row) * SEQ + p * 8, Vs + c * 8);
    }
    __syncthreads();   // full drain once (Q + bias + tile0)

    const int qrow = w * 16 + l15;
    bf16x8 qf[2];
    #pragma unroll
    for (int ks = 0; ks < 2; ++ks) {
        int pp = (ks * 4 + lh) ^ (qrow & 7);
        qf[ks] = *(const bf16x8*)(PQ + qrow * 64 + pp * 8);
    }

    const float* mk = memkv + bh * 128;
    float di = 0.f;
    #pragma unroll
    for (int ks = 0; ks < 2; ++ks)
        #pragma unroll
        for (int e = 0; e < 8; ++e)
            di += (float)qf[ks][e] * mk[ks * 32 + lh * 8 + e];
    di += __shfl_xor(di, 16, 64);
    di += __shfl_xor(di, 32, 64);

    f32x4 o[4] = {};
    float lsum = 0.f;
    bf16* Psw = PQ + w * 16 * 88;
    int cur = 0;

    for (int kt = 0; kt < SEQ / 64; ++kt) {
        if (kt < SEQ / 64 - 1) {
            #pragma unroll
            for (int it = 0; it < 2; ++it) {
                int c = it * 256 + tid;
                int row = c >> 3, part = c & 7;
                int p = part ^ (row & 7);
                gll16(Kh + (bhT + (kt + 1) * 64 + row) * 64 + p * 8,
                      Ks + (cur ^ 1) * 4096 + c * 8);
                gll16(Vt + ((size_t)bh * 64 + row) * SEQ + (kt + 1) * 64 + p * 8,
                      Vs + (cur ^ 1) * 4096 + c * 8);
            }
            vwait4();
        } else {
            vwait0();
        }
        SCHED0(); SBAR(); SCHED0();
        const bf16* Kc = Ks + cur * 4096;
        const bf16* Vc = Vs + cur * 4096;

        // S^T = K Q^T
        f32x4 s_[4] = {};
        #pragma unroll
        for (int ks = 0; ks < 2; ++ks) {
            #pragma unroll
            for (int jk = 0; jk < 4; ++jk) {
                int row = jk * 16 + l15;
                int cc = (ks * 4 + lh) ^ (row & 7);
                bf16x8 kf = *(const bf16x8*)(Kc + row * 64 + cc * 8);
                s_[jk] = MFMA_BF16(kf, qf[ks], s_[jk]);
            }
        }

        // p = 2^(s*c + bias); packed b64 P writes (lane-local q-row)
        #pragma unroll
        for (int jk = 0; jk < 4; ++jk) {
            int idx0 = (w * 16 + l15) - (kt * 64 + jk * 16 + lh * 4) + 2047;
            bf16x4 pb;
            #pragma unroll
            for (int r = 0; r < 4; ++r) {
                float pexp = exp2f(s_[jk][r] * (0.125f * LOG2E) + bias_s[idx0 - r]);
                lsum += pexp;
                pb[r] = (bf16)pexp;
            }
            *(bf16x4*)(Psw + l15 * 88 + jk * 16 + lh * 4) = pb;
        }

        // O += P V
        #pragma unroll
        for (int ks = 0; ks < 2; ++ks) {
            bf16x8 pf = *(const bf16x8*)(Psw + l15 * 88 + ks * 32 + lh * 8);
            #pragma unroll
            for (int jd = 0; jd < 4; ++jd) {
                int row = jd * 16 + l15;
                int cc = (ks * 4 + lh) ^ (row & 7);
                bf16x8 vf = *(const bf16x8*)(Vc + row * 64 + cc * 8);
                o[jd] = MFMA_BF16(pf, vf, o[jd]);
            }
        }
        SCHED0(); SBAR(); SCHED0();
        cur ^= 1;
    }

    lsum += __shfl_xor(lsum, 16, 64);
    lsum += __shfl_xor(lsum, 32, 64);

    float inv_l[4], sig[4];
    #pragma unroll
    for (int r = 0; r < 4; ++r) {
        int src = lh * 4 + r;
        inv_l[r] = 1.f / __shfl(lsum, src, 64);
        float dd = __shfl(di, src, 64);
        sig[r] = 1.f / (1.f + __expf(-dd));
    }

    const int b = bh >> 4, h = bh & 15;
    #pragma unroll
    for (int jd = 0; jd < 4; ++jd) {
        int d = jd * 16 + l15;
        float mv = mk[64 + d];
        #pragma unroll
        for (int r = 0; r < 4; ++r) {
            int qi = q0 + w * 16 + lh * 4 + r;
            float val = o[jd][r] * inv_l[r] + 0.2f * sig[r] * mv;
            ao[((size_t)(b * SEQ + qi)) * D_MODEL + h * 64 + d] = (bf16)val;
        }
    }
}

// ---------------------------------------------------------------------------
extern "C" void kernel_launch(void* const* d_in, const int* in_sizes, int n_in,
                              void* d_out, int out_size, void* d_ws, size_t ws_size,
                              hipStream_t stream)
{
    const float* x        = (const float*)d_in[0];
    const float* Wq       = (const float*)d_in[1];
    const float* bq       = (const float*)d_in[2];
    const float* Wkv_down = (const float*)d_in[3];
    const float* bkv_down = (const float*)d_in[4];
    const float* Wkv_up   = (const float*)d_in[5];
    const float* bkv_up   = (const float*)d_in[6];
    const float* Wo       = (const float*)d_in[7];
    const float* bo       = (const float*)d_in[8];
    float* out = (float*)d_out;

    char* p = (char*)d_ws;
    bf16* xb   = (bf16*)p;  p += 8388608;    // [4096][1024]
    bf16* Wqt  = (bf16*)p;  p += 2097152;
    bf16* Wdt  = (bf16*)p;  p += 524288;
    bf16* Wut  = (bf16*)p;  p += 1048576;
    bf16* Wot  = (bf16*)p;  p += 2097152;
    bf16* kvd  = (bf16*)p;  p += 2097152;    // [4096][256]
    bf16* Qh   = (bf16*)p;  p += 8388608;    // [32][2048][64]
    bf16* Kh   = (bf16*)p;  p += 8388608;
    bf16* Vt   = (bf16*)p;  p += 8388608;    // [32][64][2048]
    bf16* ao   = (bf16*)p;  p += 8388608;    // [4096][1024]
    float* memb  = (float*)p; p += 16384;    // [32][128]
    float* bias2 = (float*)p; p += 16384;    // [4095]
    float2* rtab = (float2*)p; p += 524288;  // [2048][32]

    dim3 blk(256);

    // prep: convert + transposes + tables + memb=0
    prep_all<<<dim3(5136), blk, 0, stream>>>(
        x, xb, Wq, Wqt, Wkv_down, Wdt, Wkv_up, Wut, Wo, Wot, rtab, bias2, memb);

    // merged q-proj(+RoPE) and kv-down
    gemm_qkvd<<<dim3(10, M_ROWS / 128), blk, 0, stream>>>(
        xb, Wqt, bq, rtab, Qh, Wdt, bkv_down, kvd);

    // kv-up: RoPE(k)->Kh, V->Vt (LDS transpose), means->memb (atomics)
    gemm_kv_rope<<<dim3(N_HEADS, M_ROWS / 128), blk, 0, stream>>>(
        kvd, Wut, bkv_up, rtab, Kh, Vt, memb);

    // attention (+infini fused)
    attn_mfma<<<dim3(SEQ / 64, BATCH * N_HEADS), blk, 0, stream>>>(
        Qh, Kh, Vt, bias2, memb, ao);

    // output projection
    gemm_out<<<dim3(D_MODEL / 128, M_ROWS / 128), blk, 0, stream>>>(
        ao, Wot, bo, out);
}

// Round 11
// 218.443 us; speedup vs baseline: 13.6401x; 1.0210x over previous
//
#include <hip/hip_runtime.h>
#include <hip/hip_bf16.h>

#define D_MODEL 1024
#define N_HEADS 16
#define HEAD_DIM 64
#define D_LATENT 256
#define BATCH 2
#define SEQ 2048
#define M_ROWS (BATCH * SEQ)   // 4096

typedef __bf16 bf16;
typedef __attribute__((ext_vector_type(4))) __bf16 bf16x4;
typedef __attribute__((ext_vector_type(8))) __bf16 bf16x8;
typedef __attribute__((ext_vector_type(4))) float f32x4;
typedef __attribute__((ext_vector_type(16))) float f32x16;

#define MFMA_BF16(a, b, c) __builtin_amdgcn_mfma_f32_16x16x32_bf16((a), (b), (c), 0, 0, 0)
#define MFMA32(a, b, c)    __builtin_amdgcn_mfma_f32_32x32x16_bf16((a), (b), (c), 0, 0, 0)
#define LOG2E 1.4426950408889634f
#define SBAR() __builtin_amdgcn_s_barrier()
#define SCHED0() __builtin_amdgcn_sched_barrier(0)

__device__ __forceinline__ void gll16(const void* g, void* l) {
    __builtin_amdgcn_global_load_lds(
        (const __attribute__((address_space(1))) unsigned int*)g,
        (__attribute__((address_space(3))) unsigned int*)l, 16, 0, 0);
}
__device__ __forceinline__ void vwait4() { asm volatile("s_waitcnt vmcnt(4)" ::: "memory"); }
__device__ __forceinline__ void vwait0() { asm volatile("s_waitcnt vmcnt(0)" ::: "memory"); }

// ---------------------------------------------------------------------------
// prep_all: convert x | 4x weight transpose | rope table | bias table | memb=0
// ---------------------------------------------------------------------------
__device__ __forceinline__ void tw_body(
    const float* __restrict__ W, bf16* __restrict__ Wt, int K, int N,
    int b, float (*tw)[33], int tid)
{
    int nx = N / 32;
    int n0 = (b % nx) * 32, k0 = (b / nx) * 32;
    int c = tid & 31, r = tid >> 5;
    #pragma unroll
    for (int it = 0; it < 4; ++it)
        tw[r + it * 8][c] = W[(size_t)(k0 + r + it * 8) * N + n0 + c];
    __syncthreads();
    #pragma unroll
    for (int it = 0; it < 4; ++it)
        Wt[(size_t)(n0 + r + it * 8) * K + k0 + c] = (bf16)tw[c][r + it * 8];
}

__global__ __launch_bounds__(256) void prep_all(
    const float* __restrict__ x, bf16* __restrict__ xb,
    const float* __restrict__ Wq, bf16* __restrict__ Wqt,
    const float* __restrict__ Wd, bf16* __restrict__ Wdt,
    const float* __restrict__ Wu, bf16* __restrict__ Wut,
    const float* __restrict__ Wo, bf16* __restrict__ Wot,
    float2* __restrict__ rtab, float* __restrict__ bias2,
    float* __restrict__ memb)
{
    __shared__ float tw[32][33];
    const int bid = blockIdx.x, tid = threadIdx.x;
    if (bid < 2048) {
        int i = bid * 256 + tid;
        const float4* s = ((const float4*)x) + (size_t)i * 2;
        float4 a = s[0], b = s[1];
        bf16x8 v;
        v[0] = (bf16)a.x; v[1] = (bf16)a.y; v[2] = (bf16)a.z; v[3] = (bf16)a.w;
        v[4] = (bf16)b.x; v[5] = (bf16)b.y; v[6] = (bf16)b.z; v[7] = (bf16)b.w;
        *(bf16x8*)(xb + (size_t)i * 8) = v;
    } else if (bid < 3072) {
        tw_body(Wq, Wqt, 1024, 1024, bid - 2048, tw, tid);
    } else if (bid < 3328) {
        tw_body(Wd, Wdt, 1024, 256, bid - 3072, tw, tid);
    } else if (bid < 3840) {
        tw_body(Wu, Wut, 256, 2048, bid - 3328, tw, tid);
    } else if (bid < 4864) {
        tw_body(Wo, Wot, 1024, 1024, bid - 3840, tw, tid);
    } else if (bid < 5120) {
        int i = (bid - 4864) * 256 + tid;
        int j = i & 31, t = i >> 5;
        float inv_freq = exp2f((float)j * -0.4152410118609203f);
        float ang = (float)t * inv_freq;
        float sn, cs; sincosf(ang, &sn, &cs);
        rtab[i] = make_float2(cs, sn);
    } else {
        int i = (bid - 5120) * 256 + tid;    // < 4096
        if (i < 2 * SEQ - 1) {
            float d = (float)(i - (SEQ - 1));
            float ls  = -0.1f * logf(fabsf(d) + 1.0f);
            float dec = expf(-fmaxf(d, 0.0f) * 0.01f);
            bias2[i] = (ls + logf(dec + 1e-9f)) * LOG2E;
        }
        if (i < 4096) memb[i] = 0.f;
    }
}

// ---------------------------------------------------------------------------
// Double-buffered MFMA GEMM body (128x128 tile, BK=32, 4 waves).
// ---------------------------------------------------------------------------
__device__ __forceinline__ void stage_gemm(
    const bf16* __restrict__ A, const bf16* __restrict__ Bt, int K, int k0,
    bf16* As, bf16* Bs, int m0, int n0, int tid)
{
    #pragma unroll
    for (int it = 0; it < 2; ++it) {
        int c = it * 256 + tid;          // 0..511
        int row = c >> 2, part = c & 3;
        int p = part ^ ((row >> 1) & 3);
        gll16(A  + (size_t)(m0 + row) * K + k0 + p * 8, As + c * 8);
        gll16(Bt + (size_t)(n0 + row) * K + k0 + p * 8, Bs + c * 8);
    }
}

__device__ __forceinline__ void gemm_body(
    const bf16* __restrict__ A, const bf16* __restrict__ Bt, int K,
    bf16* sh, f32x4 (&acc)[4][4],
    int m0, int n0, int tid, int l15, int lh, int wr, int wc)
{
    stage_gemm(A, Bt, K, 0, sh, sh + 8192, m0, n0, tid);
    int cur = 0;
    for (int k0 = 0; k0 < K; k0 += 32) {
        if (k0 + 32 < K) {
            stage_gemm(A, Bt, K, k0 + 32, sh + (cur ^ 1) * 4096,
                       sh + 8192 + (cur ^ 1) * 4096, m0, n0, tid);
            vwait4();
        } else {
            vwait0();
        }
        SCHED0(); SBAR(); SCHED0();
        const bf16* As = sh + cur * 4096;
        const bf16* Bs = sh + 8192 + cur * 4096;
        bf16x8 af[4], bg[4];
        #pragma unroll
        for (int i = 0; i < 4; ++i) {
            int row = wr * 64 + i * 16 + l15;
            int cc = lh ^ ((row >> 1) & 3);
            af[i] = *(const bf16x8*)(As + row * 32 + cc * 8);
        }
        #pragma unroll
        for (int j = 0; j < 4; ++j) {
            int row = wc * 64 + j * 16 + l15;
            int cc = lh ^ ((row >> 1) & 3);
            bg[j] = *(const bf16x8*)(Bs + row * 32 + cc * 8);
        }
        #pragma unroll
        for (int i = 0; i < 4; ++i)
            #pragma unroll
            for (int j = 0; j < 4; ++j)
                acc[i][j] = MFMA_BF16(af[i], bg[j], acc[i][j]);
        SCHED0(); SBAR(); SCHED0();
        cur ^= 1;
    }
}

// ---------------------------------------------------------------------------
// Merged Q-proj (+RoPE pack) and KV-down GEMM.  grid = (10, 32).
// ---------------------------------------------------------------------------
__global__ __launch_bounds__(256) void gemm_qkvd(
    const bf16* __restrict__ xb,
    const bf16* __restrict__ Wqt, const float* __restrict__ bq,
    const float2* __restrict__ rtab, bf16* __restrict__ Qh,
    const bf16* __restrict__ Wdt, const float* __restrict__ bkvd,
    bf16* __restrict__ kvd)
{
    __shared__ bf16 sh[16384];
    const int tid = threadIdx.x, lane = tid & 63, w = tid >> 6;
    const int wr = w >> 1, wc = w & 1;
    const int l15 = lane & 15, lh = lane >> 4;
    const int bx = blockIdx.x;
    const int m0 = blockIdx.y * 128;
    const bf16* Bt = (bx < 8) ? Wqt : Wdt;
    const int n0 = (bx < 8) ? bx * 128 : (bx - 8) * 128;

    f32x4 acc[4][4] = {};
    gemm_body(xb, Bt, D_MODEL, sh, acc, m0, n0, tid, l15, lh, wr, wc);

    if (bx < 8) {
        const int head = bx * 2 + wc;
        #pragma unroll
        for (int i = 0; i < 4; ++i) {
            #pragma unroll
            for (int r = 0; r < 4; ++r) {
                int m = m0 + wr * 64 + i * 16 + lh * 4 + r;
                int tpos = m & (SEQ - 1), b = m >> 11;
                bf16* orow = Qh + ((size_t)(b * N_HEADS + head) * SEQ + tpos) * 64;
                #pragma unroll
                for (int j01 = 0; j01 < 2; ++j01) {
                    int jj = j01 * 16 + l15;
                    float2 cssn = rtab[tpos * 32 + jj];
                    float v1 = acc[i][j01][r]     + bq[head * 64 + jj];
                    float v2 = acc[i][j01 + 2][r] + bq[head * 64 + jj + 32];
                    orow[jj]      = (bf16)(v1 * cssn.x - v2 * cssn.y);
                    orow[jj + 32] = (bf16)(v1 * cssn.y + v2 * cssn.x);
                }
            }
        }
    } else {
        #pragma unroll
        for (int i = 0; i < 4; ++i) {
            int row = m0 + wr * 64 + i * 16 + lh * 4;
            #pragma unroll
            for (int j = 0; j < 4; ++j) {
                int col = n0 + wc * 64 + j * 16 + l15;
                float bv = bkvd[col];
                #pragma unroll
                for (int r = 0; r < 4; ++r)
                    kvd[(size_t)(row + r) * D_LATENT + col] = (bf16)(acc[i][j][r] + bv);
            }
        }
    }
}

// ---------------------------------------------------------------------------
// KV-up GEMM: fused RoPE(k)->Kh, LDS-transpose V->Vt, mean atomics->memb.
// ---------------------------------------------------------------------------
__global__ __launch_bounds__(256) void gemm_kv_rope(
    const bf16* __restrict__ A, const bf16* __restrict__ Bt,
    const float* __restrict__ bias, const float2* __restrict__ rtab,
    bf16* __restrict__ Kh, bf16* __restrict__ Vt, float* __restrict__ memb)
{
    __shared__ bf16 sh[16384];
    const int tid = threadIdx.x, lane = tid & 63, w = tid >> 6;
    const int wr = w >> 1, wc = w & 1;
    const int l15 = lane & 15, lh = lane >> 4;
    const int head = blockIdx.x;
    const int m0 = blockIdx.y * 128;
    const int b = m0 >> 11;
    const int bh = b * N_HEADS + head;
    const int tpos0 = m0 & (SEQ - 1);

    f32x4 acc[4][4] = {};
    gemm_body(A, Bt, D_LATENT, sh, acc, m0, head * 128, tid, l15, lh, wr, wc);

    if (wc == 0) {
        float s0 = 0.f, s1 = 0.f, s2 = 0.f, s3 = 0.f;
        #pragma unroll
        for (int i = 0; i < 4; ++i) {
            #pragma unroll
            for (int r = 0; r < 4; ++r) {
                int m = m0 + wr * 64 + i * 16 + lh * 4 + r;
                int tpos = m & (SEQ - 1);
                bf16* orow = Kh + ((size_t)bh * SEQ + tpos) * 64;
                float2 ca = rtab[tpos * 32 + l15];
                float v1 = acc[i][0][r] + bias[head * 128 + l15];
                float v2 = acc[i][2][r] + bias[head * 128 + l15 + 32];
                float o1 = v1 * ca.x - v2 * ca.y;
                float o2 = v1 * ca.y + v2 * ca.x;
                orow[l15]      = (bf16)o1;
                orow[l15 + 32] = (bf16)o2;
                float2 cb = rtab[tpos * 32 + 16 + l15];
                float v3 = acc[i][1][r] + bias[head * 128 + 16 + l15];
                float v4 = acc[i][3][r] + bias[head * 128 + 48 + l15];
                float o3 = v3 * cb.x - v4 * cb.y;
                float o4 = v3 * cb.y + v4 * cb.x;
                orow[16 + l15] = (bf16)o3;
                orow[48 + l15] = (bf16)o4;
                s0 += o1; s1 += o3; s2 += o2; s3 += o4;
            }
        }
        s0 += __shfl_xor(s0, 16, 64); s0 += __shfl_xor(s0, 32, 64);
        s1 += __shfl_xor(s1, 16, 64); s1 += __shfl_xor(s1, 32, 64);
        s2 += __shfl_xor(s2, 16, 64); s2 += __shfl_xor(s2, 32, 64);
        s3 += __shfl_xor(s3, 16, 64); s3 += __shfl_xor(s3, 32, 64);
        if (lane < 16) {
            const float sc = 1.f / SEQ;
            atomicAdd(&memb[bh * 128 + l15],      s0 * sc);
            atomicAdd(&memb[bh * 128 + 16 + l15], s1 * sc);
            atomicAdd(&memb[bh * 128 + 32 + l15], s2 * sc);
            atomicAdd(&memb[bh * 128 + 48 + l15], s3 * sc);
        }
    } else {
        float sv[4] = {};
        #pragma unroll
        for (int i = 0; i < 4; ++i) {
            #pragma unroll
            for (int j = 0; j < 4; ++j) {
                int d = j * 16 + l15;
                float bv = bias[head * 128 + 64 + d];
                #pragma unroll
                for (int r = 0; r < 4; ++r) {
                    int t = wr * 64 + i * 16 + lh * 4 + r;
                    float v = acc[i][j][r] + bv;
                    sh[d * 136 + t] = (bf16)v;
                    sv[j] += v;
                }
            }
        }
        #pragma unroll
        for (int j = 0; j < 4; ++j) {
            sv[j] += __shfl_xor(sv[j], 16, 64);
            sv[j] += __shfl_xor(sv[j], 32, 64);
        }
        if (lane < 16) {
            const float sc = 1.f / SEQ;
            #pragma unroll
            for (int j = 0; j < 4; ++j)
                atomicAdd(&memb[bh * 128 + 64 + j * 16 + l15], sv[j] * sc);
        }
    }
    __syncthreads();
    {
        int d = tid >> 2, seg = tid & 3;
        bf16* dst = Vt + ((size_t)bh * 64 + d) * SEQ + tpos0 + seg * 32;
        #pragma unroll
        for (int e = 0; e < 4; ++e)
            *(bf16x8*)(dst + e * 8) = *(const bf16x8*)(sh + d * 136 + seg * 32 + e * 8);
    }
}

// ---------------------------------------------------------------------------
// Plain GEMM (o-proj): C = A @ Bt^T + bias -> f32
// ---------------------------------------------------------------------------
__global__ __launch_bounds__(256) void gemm_out(
    const bf16* __restrict__ A, const bf16* __restrict__ Bt,
    const float* __restrict__ bias, float* __restrict__ C)
{
    __shared__ bf16 sh[16384];
    const int tid = threadIdx.x, lane = tid & 63, w = tid >> 6;
    const int wr = w >> 1, wc = w & 1;
    const int l15 = lane & 15, lh = lane >> 4;
    const int m0 = blockIdx.y * 128, n0 = blockIdx.x * 128;
    f32x4 acc[4][4] = {};
    gemm_body(A, Bt, D_MODEL, sh, acc, m0, n0, tid, l15, lh, wr, wc);

    #pragma unroll
    for (int i = 0; i < 4; ++i) {
        int row = m0 + wr * 64 + i * 16 + lh * 4;
        #pragma unroll
        for (int j = 0; j < 4; ++j) {
            int col = n0 + wc * 64 + j * 16 + l15;
            float bv = bias[col];
            #pragma unroll
            for (int r = 0; r < 4; ++r)
                C[(size_t)(row + r) * D_MODEL + col] = acc[i][j][r] + bv;
        }
    }
}

// ---------------------------------------------------------------------------
// MFMA flash attention, 32x32 MFMAs, P-in-register via shfl exchange,
// no-max softmax, fused infini.  grid = 1024 (XCD-swizzled), 128 threads
// (2 waves x 32 q-rows), QBLK=64, KVBLK=64.  LDS ~24.8 KB.
// ---------------------------------------------------------------------------
__global__ __launch_bounds__(128) void attn_mfma(
    const bf16* __restrict__ Qh,     // [BH][T][64]
    const bf16* __restrict__ Kh,     // [BH][T][64]
    const bf16* __restrict__ Vt,     // [BH][64][T]
    const float* __restrict__ bias2, // [4095], * log2e
    const float* __restrict__ memkv, // [BH][128]
    bf16* __restrict__ ao)           // [B][T][H][64]
{
    __shared__ bf16 KV[8192];        // Qs (8KB, aliased) then K(8KB)|V(8KB)
    __shared__ float bias_s[2112];

    const int tid = threadIdx.x;
    const int lane = tid & 63;
    const int w = tid >> 6;            // 0..1
    const int l31 = lane & 31, h5 = lane >> 5;
    // XCD-aware decode: 8 XCDs x 4 bh x 32 q-blocks (bijective, 1024 blocks)
    const int B = blockIdx.x;
    const int loc = B >> 3;
    const int bh = (B & 7) * 4 + (loc >> 5);
    const int q0 = (loc & 31) * 64;
    const size_t bhT = (size_t)bh * SEQ;
    const int b = bh >> 4, h = bh & 15;

    for (int i = tid; i < 2111; i += 128) bias_s[i] = bias2[q0 + i];
    #pragma unroll
    for (int it = 0; it < 4; ++it) {
        int c = it * 128 + tid;          // 0..511
        int row = c >> 3, part = c & 7;
        int p = part ^ (row & 7);
        gll16(Qh + (bhT + q0 + row) * 64 + p * 8, KV + c * 8);
    }
    __syncthreads();

    // Q B-frags: col q = w*32 + l31, k = kg*16 + h5*8 + e
    const int qrow = w * 32 + l31;
    bf16x8 qf[4];
    #pragma unroll
    for (int kg = 0; kg < 4; ++kg) {
        int pp = (kg * 2 + h5) ^ (qrow & 7);
        qf[kg] = *(const bf16x8*)(KV + qrow * 64 + pp * 8);
    }
    const float* mk = memkv + bh * 128;
    float di = 0.f;
    #pragma unroll
    for (int kg = 0; kg < 4; ++kg)
        #pragma unroll
        for (int e = 0; e < 8; ++e)
            di += (float)qf[kg][e] * mk[kg * 16 + h5 * 8 + e];
    di += __shfl_xor(di, 32, 64);
    __syncthreads();   // Q-frag reads done -> KV region reusable

    bf16* Ks = KV;
    bf16* Vs = KV + 4096;
    f32x16 o0 = {}, o1 = {};
    float lsum = 0.f;
    const float C1 = 0.125f * LOG2E;

    for (int kt = 0; kt < SEQ / 64; ++kt) {
        #pragma unroll
        for (int it = 0; it < 4; ++it) {
            int c = it * 128 + tid;
            int row = c >> 3, part = c & 7;
            int p = part ^ (row & 7);
            gll16(Kh + (bhT + kt * 64 + row) * 64 + p * 8, Ks + c * 8);
            gll16(Vt + ((size_t)bh * 64 + row) * SEQ + kt * 64 + p * 8, Vs + c * 8);
        }
        __syncthreads();

        // S^T[kv][q] = K Q^T : 2 kv-groups x 4 k-groups of 32x32x16
        f32x16 s0 = {}, s1 = {};
        __builtin_amdgcn_s_setprio(1);
        #pragma unroll
        for (int kg = 0; kg < 4; ++kg) {
            int pp = (kg * 2 + h5) ^ (l31 & 7);
            bf16x8 kf0 = *(const bf16x8*)(Ks + l31 * 64 + pp * 8);
            bf16x8 kf1 = *(const bf16x8*)(Ks + (32 + l31) * 64 + pp * 8);
            s0 = MFMA32(kf0, qf[kg], s0);
            s1 = MFMA32(kf1, qf[kg], s1);
        }
        __builtin_amdgcn_s_setprio(0);

        // p = 2^(s*c + bias) for lane's q = l31; pack bf16x4 quads
        uint2 qd[8];
        auto mkquads = [&](const f32x16& sg, int g) {
            #pragma unroll
            for (int rq = 0; rq < 4; ++rq) {
                int base = kt * 64 + g * 32 + rq * 8 + h5 * 4;
                int bidx = (w * 32 + l31) - base + 2047;
                union { bf16x4 v; uint2 u; } pk;
                #pragma unroll
                for (int j = 0; j < 4; ++j) {
                    float pe = exp2f(sg[rq * 4 + j] * C1 + bias_s[bidx - j]);
                    lsum += pe;
                    pk.v[j] = (bf16)pe;
                }
                qd[g * 4 + rq] = pk.u;
            }
        };
        mkquads(s0, 0);
        mkquads(s1, 1);

        // O += P V : exchange cross-half quads via shfl_xor(32), PV MFMAs
        #pragma unroll
        for (int c = 0; c < 4; ++c) {
            uint2 own = h5 ? qd[2 * c + 1] : qd[2 * c];
            uint2 sup = h5 ? qd[2 * c]     : qd[2 * c + 1];
            uint2 rec;
            rec.x = (unsigned)__shfl_xor((int)sup.x, 32, 64);
            rec.y = (unsigned)__shfl_xor((int)sup.y, 32, 64);
            uint2 lo = h5 ? rec : own;
            uint2 hi = h5 ? own : rec;
            union { unsigned u[4]; bf16x8 v; } pa;
            pa.u[0] = lo.x; pa.u[1] = lo.y; pa.u[2] = hi.x; pa.u[3] = hi.y;
            int pp = (c * 2 + h5) ^ (l31 & 7);
            bf16x8 vf0 = *(const bf16x8*)(Vs + l31 * 64 + pp * 8);
            bf16x8 vf1 = *(const bf16x8*)(Vs + (32 + l31) * 64 + pp * 8);
            __builtin_amdgcn_s_setprio(1);
            o0 = MFMA32(pa.v, vf0, o0);
            o1 = MFMA32(pa.v, vf1, o1);
            __builtin_amdgcn_s_setprio(0);
        }
        __syncthreads();
    }

    // totals: lsum/di cover q = w*32 + l31 after cross-half add
    lsum += __shfl_xor(lsum, 32, 64);
    float* inv_s = bias_s;           // reuse (post final barrier)
    float* sig_s = bias_s + 64;
    if (h5 == 0) {
        inv_s[qrow] = 1.f / lsum;
        sig_s[qrow] = 1.f / (1.f + __expf(-di));
    }
    float mv0 = mk[64 + l31], mv1 = mk[96 + l31];
    #pragma unroll
    for (int rq = 0; rq < 4; ++rq) {
        #pragma unroll
        for (int j = 0; j < 4; ++j) {
            int qr = w * 32 + j + rq * 8 + h5 * 4;
            float il = inv_s[qr];
            float sg = sig_s[qr];
            int qi = q0 + qr;
            float v0 = o0[rq * 4 + j] * il + 0.2f * sg * mv0;
            float v1 = o1[rq * 4 + j] * il + 0.2f * sg * mv1;
            bf16* op = ao + ((size_t)(b * SEQ + qi)) * D_MODEL + h * 64;
            op[l31]      = (bf16)v0;
            op[32 + l31] = (bf16)v1;
        }
    }
}

// ---------------------------------------------------------------------------
extern "C" void kernel_launch(void* const* d_in, const int* in_sizes, int n_in,
                              void* d_out, int out_size, void* d_ws, size_t ws_size,
                              hipStream_t stream)
{
    const float* x        = (const float*)d_in[0];
    const float* Wq       = (const float*)d_in[1];
    const float* bq       = (const float*)d_in[2];
    const float* Wkv_down = (const float*)d_in[3];
    const float* bkv_down = (const float*)d_in[4];
    const float* Wkv_up   = (const float*)d_in[5];
    const float* bkv_up   = (const float*)d_in[6];
    const float* Wo       = (const float*)d_in[7];
    const float* bo       = (const float*)d_in[8];
    float* out = (float*)d_out;

    char* p = (char*)d_ws;
    bf16* xb   = (bf16*)p;  p += 8388608;    // [4096][1024]
    bf16* Wqt  = (bf16*)p;  p += 2097152;
    bf16* Wdt  = (bf16*)p;  p += 524288;
    bf16* Wut  = (bf16*)p;  p += 1048576;
    bf16* Wot  = (bf16*)p;  p += 2097152;
    bf16* kvd  = (bf16*)p;  p += 2097152;    // [4096][256]
    bf16* Qh   = (bf16*)p;  p += 8388608;    // [32][2048][64]
    bf16* Kh   = (bf16*)p;  p += 8388608;
    bf16* Vt   = (bf16*)p;  p += 8388608;    // [32][64][2048]
    bf16* ao   = (bf16*)p;  p += 8388608;    // [4096][1024]
    float* memb  = (float*)p; p += 16384;    // [32][128]
    float* bias2 = (float*)p; p += 16384;    // [4095]
    float2* rtab = (float2*)p; p += 524288;  // [2048][32]

    dim3 blk(256);

    prep_all<<<dim3(5136), blk, 0, stream>>>(
        x, xb, Wq, Wqt, Wkv_down, Wdt, Wkv_up, Wut, Wo, Wot, rtab, bias2, memb);

    gemm_qkvd<<<dim3(10, M_ROWS / 128), blk, 0, stream>>>(
        xb, Wqt, bq, rtab, Qh, Wdt, bkv_down, kvd);

    gemm_kv_rope<<<dim3(N_HEADS, M_ROWS / 128), blk, 0, stream>>>(
        kvd, Wut, bkv_up, rtab, Kh, Vt, memb);

    attn_mfma<<<dim3(1024), dim3(128), 0, stream>>>(
        Qh, Kh, Vt, bias2, memb, ao);

    gemm_out<<<dim3(D_MODEL / 128, M_ROWS / 128), blk, 0, stream>>>(
        ao, Wot, bo, out);
}